// Round 9
// baseline (2057.339 us; speedup 1.0000x reference)
//
#include <hip/hip_runtime.h>
#include <math.h>

#define NN 2048
#define EE 65536
#define T_OBS 6
#define FIN 2
#define HE 256
#define LT 128
#define PREDN 6
#define DMM_NZ 8
#define ZR_NZ 4
#define GT_NZ 8
#define LIN_NZ 8

typedef __attribute__((ext_vector_type(8))) short short8v;
typedef __attribute__((ext_vector_type(4))) short short4v;
typedef __attribute__((ext_vector_type(4))) float float4v;

static __device__ __forceinline__ unsigned short f2bf(float f) {
    union { float f; unsigned u; } v; v.f = f;
    unsigned r = v.u + 0x7fff + ((v.u >> 16) & 1);
    return (unsigned short)(r >> 16);
}

// truncation split: f ~= hi + lo
static __device__ __forceinline__ void bfsplit(float f, unsigned short& h,
                                               unsigned short& l) {
    unsigned u = __float_as_uint(f);
    h = (unsigned short)(u >> 16);
    float hf = __uint_as_float(u & 0xffff0000u);
    l = (unsigned short)(__float_as_uint(f - hf) >> 16);
}

static __device__ __forceinline__ void split4(float4 v, short4v& h, short4v& l) {
    unsigned short hh, ll;
    bfsplit(v.x, hh, ll); h[0] = (short)hh; l[0] = (short)ll;
    bfsplit(v.y, hh, ll); h[1] = (short)hh; l[1] = (short)ll;
    bfsplit(v.z, hh, ll); h[2] = (short)hh; l[2] = (short)ll;
    bfsplit(v.w, hh, ll); h[3] = (short)hh; l[3] = (short)ll;
}

static __device__ __forceinline__ float bf2f(unsigned short b) {
    return __uint_as_float(((unsigned)b) << 16);
}

// ---------------- one-time prep ----------------
// in: [S][K][N] fp32 (S = blockIdx.y) -> out hi/lo [S][N][K] bf16
__global__ void k_tsplit(const float* __restrict__ in, unsigned short* __restrict__ oh,
                         unsigned short* __restrict__ ol, int K, int N) {
    size_t base = (size_t)blockIdx.y * K * N;
    int idx = blockIdx.x * 256 + threadIdx.x;
    if (idx < K * N) {
        int k = idx / N, n = idx - k * N;
        unsigned short h, l;
        bfsplit(in[base + idx], h, l);
        oh[base + (size_t)n * K + k] = h;
        ol[base + (size_t)n * K + k] = l;
    }
}

__global__ void k_cvt(const float* __restrict__ in, unsigned short* __restrict__ oh,
                      unsigned short* __restrict__ ol, int n4) {
    int i = blockIdx.x * 256 + threadIdx.x;
    if (i < n4) {
        float4 v = ((const float4*)in)[i];
        short4v h, l;
        split4(v, h, l);
        *(short4v*)&oh[(size_t)i * 4] = h;
        *(short4v*)&ol[(size_t)i * 4] = l;
    }
}

// ---------------- sparse graph prep ----------------
__global__ void k_degcnt(const int* __restrict__ src, const int* __restrict__ dst,
                         const float* __restrict__ ew,
                         float* __restrict__ deg, int* __restrict__ cnt) {
    int e = blockIdx.x * blockDim.x + threadIdx.x;
    if (e < EE) {
        atomicAdd(&deg[src[e]], ew[e]);
        atomicAdd(&cnt[dst[e]], 1);
    }
}

__global__ void k_scan(const int* __restrict__ cnt, const float* __restrict__ deg,
                       int* __restrict__ roff, int* __restrict__ cur,
                       float* __restrict__ dinv) {
    __shared__ int part[256];
    int t = threadIdx.x;
#pragma unroll
    for (int i = t; i < NN; i += 256) {
        float d = deg[i];
        dinv[i] = d > 0.f ? 1.f / sqrtf(d) : 0.f;
    }
    int loc[8];
    int s = 0;
#pragma unroll
    for (int i = 0; i < 8; i++) { loc[i] = cnt[t * 8 + i]; s += loc[i]; }
    part[t] = s;
    __syncthreads();
    for (int off = 1; off < 256; off <<= 1) {
        int v = (t >= off) ? part[t - off] : 0;
        __syncthreads();
        part[t] += v;
        __syncthreads();
    }
    int run = (t == 0) ? 0 : part[t - 1];
#pragma unroll
    for (int i = 0; i < 8; i++) {
        int idx = t * 8 + i;
        roff[idx] = run;
        cur[idx] = run;
        run += loc[i];
    }
    if (t == 255) roff[NN] = run;
}

__global__ void k_scatter2(const int* __restrict__ src, const int* __restrict__ dst,
                           const float* __restrict__ ew, const float* __restrict__ dinv,
                           int* __restrict__ cur,
                           int* __restrict__ csr_src, float* __restrict__ csr_nrm) {
    int e = blockIdx.x * blockDim.x + threadIdx.x;
    if (e < EE) {
        int s = src[e], d = dst[e];
        int p = atomicAdd(&cur[d], 1);
        csr_src[p] = s;
        csr_nrm[p] = -dinv[s] * ew[e] * dinv[d];
    }
}

// CSR SpMM, wave per node, float4 per lane, 8 edges batched; emits fp32 + hi/lo bf16
template <int F>
__global__ void k_spmm_v(const int* __restrict__ roff, const int* __restrict__ csr_src,
                         const float* __restrict__ csr_nrm,
                         const float* __restrict__ X, float* __restrict__ out,
                         unsigned short* __restrict__ oh, unsigned short* __restrict__ ol) {
    int w = threadIdx.x >> 6, lane = threadIdx.x & 63;
    int nid = (blockIdx.x << 2) + w;
    int c = lane << 2;
    int s0 = roff[nid], s1 = roff[nid + 1];
    float4 acc = make_float4(0.f, 0.f, 0.f, 0.f);
    int s = s0;
    for (; s + 8 <= s1; s += 8) {
        int is[8]; float ws[8];
#pragma unroll
        for (int j = 0; j < 8; j++) { is[j] = csr_src[s + j]; ws[j] = csr_nrm[s + j]; }
        if (c < F) {
            float4 xv[8];
#pragma unroll
            for (int j = 0; j < 8; j++) xv[j] = *(const float4*)&X[(size_t)is[j] * F + c];
#pragma unroll
            for (int j = 0; j < 8; j++) {
                acc.x = fmaf(ws[j], xv[j].x, acc.x);
                acc.y = fmaf(ws[j], xv[j].y, acc.y);
                acc.z = fmaf(ws[j], xv[j].z, acc.z);
                acc.w = fmaf(ws[j], xv[j].w, acc.w);
            }
        }
    }
    for (; s < s1; ++s) {
        int i0 = csr_src[s]; float w0 = csr_nrm[s];
        if (c < F) {
            float4 xv = *(const float4*)&X[(size_t)i0 * F + c];
            acc.x = fmaf(w0, xv.x, acc.x);
            acc.y = fmaf(w0, xv.y, acc.y);
            acc.z = fmaf(w0, xv.z, acc.z);
            acc.w = fmaf(w0, xv.w, acc.w);
        }
    }
    if (c < F) {
        *(float4*)&out[(size_t)nid * F + c] = acc;
        short4v h, l;
        split4(acc, h, l);
        *(short4v*)&oh[(size_t)nid * F + c] = h;
        *(short4v*)&ol[(size_t)nid * F + c] = l;
    }
}

__global__ void k_spmm2(const int* __restrict__ roff, const int* __restrict__ csr_src,
                        const float* __restrict__ csr_nrm,
                        const float* __restrict__ X, float* __restrict__ out) {
    int nid = blockIdx.x * blockDim.x + threadIdx.x;
    if (nid < NN) {
        int s0 = roff[nid], s1 = roff[nid + 1];
        float a0 = 0.f, a1 = 0.f;
        for (int s = s0; s < s1; ++s) {
            int i = csr_src[s]; float w = csr_nrm[s];
            float2 xv = *(const float2*)&X[2 * i];
            a0 = fmaf(w, xv.x, a0);
            a1 = fmaf(w, xv.y, a1);
        }
        out[2 * nid] = a0;
        out[2 * nid + 1] = a1;
    }
}

// ---------------- dense graph prep (rollout) ----------------
__global__ void k_ddeg(const float* __restrict__ c, float* __restrict__ dinv) {
    int i = blockIdx.x;
    int t = threadIdx.x;
    float xi = c[2 * i], yi = c[2 * i + 1];
    float s = 0.f;
    for (int j = t; j < NN; j += 256) {
        float dx = xi - c[2 * j], dy = yi - c[2 * j + 1];
        float d = sqrtf(dx * dx + dy * dy);
        if (d > 0.f && d < 0.5f) s += 2.f * d;
    }
    __shared__ float red[256];
    red[t] = s;
    __syncthreads();
    for (int off = 128; off > 0; off >>= 1) {
        if (t < off) red[t] += red[t + off];
        __syncthreads();
    }
    if (t == 0) {
        float d = red[0];
        dinv[i] = d > 0.f ? 1.f / sqrtf(d) : 0.f;
    }
}

// bf16 M only
__global__ void k_dM(const float* __restrict__ c, const float* __restrict__ dinv,
                     unsigned short* __restrict__ Mb) {
    int idx = blockIdx.x * blockDim.x + threadIdx.x;
    int i = idx >> 11, j = idx & (NN - 1);
    float dx = c[2 * i] - c[2 * j], dy = c[2 * i + 1] - c[2 * j + 1];
    float d = sqrtf(dx * dx + dy * dy);
    float w = (d > 0.f && d < 0.5f) ? 2.f * d : 0.f;
    Mb[idx] = f2bf(-(dinv[i] * w) * dinv[j]);
}

// dense agg via bf16 MFMA (unchanged working core from r7/r8)
template <int F>
__global__ __launch_bounds__(256) void k_dmm_mf(
    const unsigned short* __restrict__ Mb, const float* __restrict__ X,
    float* __restrict__ pbuf)
{
    __shared__ __align__(16) unsigned short Ms[64][72];
    __shared__ __align__(16) unsigned short Xs[64][72];
    const int tid = threadIdx.x;
    const int wid = tid >> 6, lane = tid & 63;
    const int m0 = blockIdx.x << 6, n0 = blockIdx.y << 6;
    const int kb0 = blockIdx.z << 8;
    const int lr = lane & 15;
    const int kg = lane >> 4;
    float4v acc[4];
#pragma unroll
    for (int t = 0; t < 4; t++) acc[t] = (float4v){0.f, 0.f, 0.f, 0.f};

    for (int kb = kb0; kb < kb0 + 256; kb += 64) {
#pragma unroll
        for (int it = 0; it < 2; it++) {
            int i = tid + it * 256;
            int r = i >> 3, c8 = (i & 7) << 3;
            *(short8v*)&Ms[r][c8] =
                *(const short8v*)&Mb[(size_t)(m0 + r) * NN + kb + c8];
        }
#pragma unroll
        for (int it = 0; it < 2; it++) {
            int i = tid + it * 256;
            int k2 = (i & 31) << 1;
            int n4 = (i >> 5) << 2;
            float4 va = *(const float4*)&X[(size_t)(kb + k2) * F + n0 + n4];
            float4 vb = *(const float4*)&X[(size_t)(kb + k2 + 1) * F + n0 + n4];
            unsigned pk;
            pk = (unsigned)f2bf(va.x) | ((unsigned)f2bf(vb.x) << 16);
            *(unsigned*)&Xs[n4 + 0][k2] = pk;
            pk = (unsigned)f2bf(va.y) | ((unsigned)f2bf(vb.y) << 16);
            *(unsigned*)&Xs[n4 + 1][k2] = pk;
            pk = (unsigned)f2bf(va.z) | ((unsigned)f2bf(vb.z) << 16);
            *(unsigned*)&Xs[n4 + 2][k2] = pk;
            pk = (unsigned)f2bf(va.w) | ((unsigned)f2bf(vb.w) << 16);
            *(unsigned*)&Xs[n4 + 3][k2] = pk;
        }
        __syncthreads();
#pragma unroll
        for (int kh = 0; kh < 2; kh++) {
            int kk = kh * 32 + kg * 8;
            short8v a = *(const short8v*)&Ms[(wid << 4) + lr][kk];
#pragma unroll
            for (int t = 0; t < 4; t++) {
                short8v b = *(const short8v*)&Xs[(t << 4) + lr][kk];
                acc[t] = __builtin_amdgcn_mfma_f32_16x16x32_bf16(a, b, acc[t], 0, 0, 0);
            }
        }
        __syncthreads();
    }
    float* p = pbuf + (size_t)blockIdx.z * NN * F;
#pragma unroll
    for (int t = 0; t < 4; t++)
#pragma unroll
        for (int j = 0; j < 4; j++)
            p[(size_t)(m0 + (wid << 4) + (kg << 2) + j) * F + n0 + (t << 4) + lr] =
                acc[t][j];
}

template <int F, int NZ>
__global__ void k_redks(const float* __restrict__ pbuf, float* __restrict__ out,
                        unsigned short* __restrict__ oh, unsigned short* __restrict__ ol) {
    const int TOT = NN * F / 4;
    int i = blockIdx.x * blockDim.x + threadIdx.x;
    if (i < TOT) {
        const float4* p = (const float4*)pbuf;
        float4 s = p[i];
#pragma unroll
        for (int z = 1; z < NZ; z++) {
            float4 v = p[(size_t)z * TOT + i];
            s.x += v.x; s.y += v.y; s.z += v.z; s.w += v.w;
        }
        ((float4*)out)[i] = s;
        short4v h, l;
        split4(s, h, l);
        *(short4v*)&oh[(size_t)i * 4] = h;
        *(short4v*)&ol[(size_t)i * 4] = l;
    }
}

// F=2 dense agg from bf16 M
__global__ void k_dmv2b(const unsigned short* __restrict__ Mb, const float* __restrict__ X,
                        float* __restrict__ out) {
    int i = blockIdx.x;
    int t = threadIdx.x;
    float a0 = 0.f, a1 = 0.f;
    for (int j = t; j < NN; j += 256) {
        float m = bf2f(Mb[(size_t)i * NN + j]);
        a0 = fmaf(m, X[2 * j], a0);
        a1 = fmaf(m, X[2 * j + 1], a1);
    }
    __shared__ float r0[256], r1[256];
    r0[t] = a0;
    r1[t] = a1;
    __syncthreads();
    for (int off = 128; off > 0; off >>= 1) {
        if (t < off) { r0[t] += r0[t + off]; r1[t] += r1[t + off]; }
        __syncthreads();
    }
    if (t == 0) { out[2 * i] = r0[0]; out[2 * i + 1] = r1[0]; }
}

// ---------------- unified pre-split bf16x3 MFMA GEMM ----------------
struct Seg {
    const unsigned short* ah; const unsigned short* al;   // A hi/lo [m][k]
    const unsigned short* bh; const unsigned short* bl;   // B hi/lo [n][k] (transposed)
    int lda, ldk, K; size_t gstride;                      // gstride: B offset per gate g
};
struct Seg4 { Seg s[4]; };

__global__ __launch_bounds__(256) void k_mf_ks(
    Seg4 segs, int nseg, int totK, int nz, int useG, int ldp,
    float* __restrict__ pbuf)
{
    __shared__ __align__(16) unsigned short Ah[64][40], Al[64][40],
                                            Bh[64][40], Bl[64][40];
    int tid = threadIdx.x;
    int wid = tid >> 6, lane = tid & 63, lr = lane & 15, kg = lane >> 4;
    int m0 = blockIdx.x << 6;
    int g = useG ? (int)(blockIdx.y >> 2) : 0;
    int n0 = useG ? (int)((blockIdx.y & 3) << 6) : (int)(blockIdx.y << 6);
    float4v acc[4];
#pragma unroll
    for (int t = 0; t < 4; t++) acc[t] = (float4v){0.f, 0.f, 0.f, 0.f};
    int chunk = totK / nz;
    int lo = blockIdx.z * chunk, hi = lo + chunk;
    int off = 0;
    int r = tid >> 2, k8 = (tid & 3) << 3;
    for (int s = 0; s < nseg; s++) {
        Seg sg = segs.s[s];
        int a = lo - off; if (a < 0) a = 0;
        int b = hi - off; if (b > sg.K) b = sg.K;
        if (b > a) {
            const unsigned short* bhp = sg.bh + (size_t)g * sg.gstride;
            const unsigned short* blp = sg.bl + (size_t)g * sg.gstride;
            for (int k0 = a; k0 < b; k0 += 32) {
                *(short8v*)&Ah[r][k8] =
                    *(const short8v*)&sg.ah[(size_t)(m0 + r) * sg.lda + k0 + k8];
                *(short8v*)&Al[r][k8] =
                    *(const short8v*)&sg.al[(size_t)(m0 + r) * sg.lda + k0 + k8];
                *(short8v*)&Bh[r][k8] =
                    *(const short8v*)&bhp[(size_t)(n0 + r) * sg.ldk + k0 + k8];
                *(short8v*)&Bl[r][k8] =
                    *(const short8v*)&blp[(size_t)(n0 + r) * sg.ldk + k0 + k8];
                __syncthreads();
                short8v ahv = *(short8v*)&Ah[(wid << 4) + lr][kg << 3];
                short8v alv = *(short8v*)&Al[(wid << 4) + lr][kg << 3];
#pragma unroll
                for (int t = 0; t < 4; t++) {
                    short8v bhv = *(short8v*)&Bh[(t << 4) + lr][kg << 3];
                    short8v blv = *(short8v*)&Bl[(t << 4) + lr][kg << 3];
                    acc[t] = __builtin_amdgcn_mfma_f32_16x16x32_bf16(ahv, bhv, acc[t], 0, 0, 0);
                    acc[t] = __builtin_amdgcn_mfma_f32_16x16x32_bf16(ahv, blv, acc[t], 0, 0, 0);
                    acc[t] = __builtin_amdgcn_mfma_f32_16x16x32_bf16(alv, bhv, acc[t], 0, 0, 0);
                }
                __syncthreads();
            }
        }
        off += sg.K;
    }
    float* p = pbuf + (size_t)blockIdx.z * NN * ldp;
    int cbase = (useG ? (g << 8) : 0) + n0;
#pragma unroll
    for (int t = 0; t < 4; t++)
#pragma unroll
        for (int j = 0; j < 4; j++)
            p[(size_t)(m0 + (wid << 4) + (kg << 2) + j) * ldp + cbase + (t << 4) + lr] =
                acc[t][j];
}

// ---------------- epilogues ----------------
__global__ void k_zr_ep(const float* __restrict__ pbuf,
                        const float* __restrict__ bx, const float* __restrict__ bh,
                        const float* __restrict__ H,
                        const float* __restrict__ x2, const float* __restrict__ ax2,
                        const float* __restrict__ Wx,
                        float* __restrict__ gz, float* __restrict__ hr,
                        unsigned short* __restrict__ hrh, unsigned short* __restrict__ hrl)
{
    int i = blockIdx.x * 256 + threadIdx.x;  // < NN*512/4
    const float4* p = (const float4*)pbuf;
    const size_t S = (size_t)NN * 512 / 4;
    float4 a = p[i];
#pragma unroll
    for (int z = 1; z < ZR_NZ; z++) {
        float4 v = p[(size_t)z * S + i];
        a.x += v.x; a.y += v.y; a.z += v.z; a.w += v.w;
    }
    int row = i >> 7, c = (i & 127) << 2;
    int g = c >> 8, cc = c & 255;
    if (Wx) {
        float x0 = x2[2 * row], x1 = x2[2 * row + 1];
        float q0 = ax2[2 * row], q1 = ax2[2 * row + 1];
        const float* W0 = Wx + (size_t)(g * 2 + 0) * FIN * HE;
        const float* W1 = Wx + (size_t)(g * 2 + 1) * FIN * HE;
        float4 w00 = *(const float4*)&W0[cc];
        float4 w01 = *(const float4*)&W0[HE + cc];
        float4 w10 = *(const float4*)&W1[cc];
        float4 w11 = *(const float4*)&W1[HE + cc];
        a.x += x0 * w00.x + x1 * w01.x + q0 * w10.x + q1 * w11.x;
        a.y += x0 * w00.y + x1 * w01.y + q0 * w10.y + q1 * w11.y;
        a.z += x0 * w00.z + x1 * w01.z + q0 * w10.z + q1 * w11.z;
        a.w += x0 * w00.w + x1 * w01.w + q0 * w10.w + q1 * w11.w;
    }
    float4 b0 = *(const float4*)&bx[c];
    float4 b1 = *(const float4*)&bh[c];
    float4 s;
    s.x = 1.f / (1.f + expf(-(a.x + b0.x + b1.x)));
    s.y = 1.f / (1.f + expf(-(a.y + b0.y + b1.y)));
    s.z = 1.f / (1.f + expf(-(a.z + b0.z + b1.z)));
    s.w = 1.f / (1.f + expf(-(a.w + b0.w + b1.w)));
    if (c < HE) {
        *(float4*)&gz[(size_t)row * HE + c] = s;
    } else {
        size_t idx = (size_t)row * HE + cc;
        float4 h = *(const float4*)&H[idx];
        s.x *= h.x; s.y *= h.y; s.z *= h.z; s.w *= h.w;
        *(float4*)&hr[idx] = s;
        short4v sh, sl;
        split4(s, sh, sl);
        *(short4v*)&hrh[idx] = sh;
        *(short4v*)&hrl[idx] = sl;
    }
}

__global__ void k_gt_ep(const float* __restrict__ pbuf,
                        const float* __restrict__ bx2, const float* __restrict__ bh2,
                        const float* __restrict__ gz,
                        const float* __restrict__ x2, const float* __restrict__ ax2,
                        const float* __restrict__ Wx2,
                        float* __restrict__ H,
                        unsigned short* __restrict__ Hh, unsigned short* __restrict__ Hl,
                        unsigned short* __restrict__ rhh, unsigned short* __restrict__ rhl)
{
    int i = blockIdx.x * 256 + threadIdx.x;  // < NN*256/4
    const float4* p = (const float4*)pbuf;
    const size_t S = (size_t)NN * HE / 4;
    float4 a = p[i];
#pragma unroll
    for (int z = 1; z < GT_NZ; z++) {
        float4 v = p[(size_t)z * S + i];
        a.x += v.x; a.y += v.y; a.z += v.z; a.w += v.w;
    }
    int row = i >> 6, c = (i & 63) << 2;
    if (Wx2) {
        float x0 = x2[2 * row], x1 = x2[2 * row + 1];
        float q0 = ax2[2 * row], q1 = ax2[2 * row + 1];
        float4 w00 = *(const float4*)&Wx2[c];
        float4 w01 = *(const float4*)&Wx2[HE + c];
        float4 w10 = *(const float4*)&Wx2[2 * HE + c];
        float4 w11 = *(const float4*)&Wx2[3 * HE + c];
        a.x += x0 * w00.x + x1 * w01.x + q0 * w10.x + q1 * w11.x;
        a.y += x0 * w00.y + x1 * w01.y + q0 * w10.y + q1 * w11.y;
        a.z += x0 * w00.z + x1 * w01.z + q0 * w10.z + q1 * w11.z;
        a.w += x0 * w00.w + x1 * w01.w + q0 * w10.w + q1 * w11.w;
    }
    float4 b0 = *(const float4*)&bx2[c];
    float4 b1 = *(const float4*)&bh2[c];
    size_t idx = (size_t)row * HE + c;
    float4 z = *(const float4*)&gz[idx];
    float4 h = *(const float4*)&H[idx];
    float4 o;
    o.x = z.x * h.x + (1.f - z.x) * tanhf(a.x + b0.x + b1.x);
    o.y = z.y * h.y + (1.f - z.y) * tanhf(a.y + b0.y + b1.y);
    o.z = z.z * h.z + (1.f - z.z) * tanhf(a.z + b0.z + b1.z);
    o.w = z.w * h.w + (1.f - z.w) * tanhf(a.w + b0.w + b1.w);
    *(float4*)&H[idx] = o;
    short4v sh, sl;
    split4(o, sh, sl);
    *(short4v*)&Hh[idx] = sh;
    *(short4v*)&Hl[idx] = sl;
    if (rhh) {
        float4 rr;
        rr.x = fmaxf(o.x, 0.f); rr.y = fmaxf(o.y, 0.f);
        rr.z = fmaxf(o.z, 0.f); rr.w = fmaxf(o.w, 0.f);
        split4(rr, sh, sl);
        *(short4v*)&rhh[idx] = sh;
        *(short4v*)&rhl[idx] = sl;
    }
}

__global__ void k_lin_ep(const float* __restrict__ pbuf,
                         const float* __restrict__ bias, float* __restrict__ out,
                         unsigned short* __restrict__ oh, unsigned short* __restrict__ ol)
{
    int i = blockIdx.x * 256 + threadIdx.x;  // < NN*128/4
    const float4* p = (const float4*)pbuf;
    const size_t S = (size_t)NN * LT / 4;
    int c = (i & 31) << 2;
    float4 bb = *(const float4*)&bias[c];
    float4 s = make_float4(bb.x, bb.y, bb.z, bb.w);
#pragma unroll
    for (int z = 0; z < LIN_NZ; z++) {
        float4 v = p[z * S + i];
        s.x += v.x; s.y += v.y; s.z += v.z; s.w += v.w;
    }
    ((float4*)out)[i] = s;
    short4v sh, sl;
    split4(s, sh, sl);
    *(short4v*)&oh[(size_t)i * 4] = sh;
    *(short4v*)&ol[(size_t)i * 4] = sl;
}

// y_hat = relu(H) @ dlinW + dlinb : one wave per row
__global__ void k_declin(const float* __restrict__ A, const float* __restrict__ B,
                         const float* __restrict__ bias, float* __restrict__ out) {
    int w = threadIdx.x >> 6, lane = threadIdx.x & 63;
    int m = blockIdx.x * 4 + w;
    float4 a = *(const float4*)&A[(size_t)m * HE + (lane << 2)];
    float av[4] = {a.x, a.y, a.z, a.w};
    float a0 = 0.f, a1 = 0.f;
#pragma unroll
    for (int j = 0; j < 4; j++) {
        float v = fmaxf(av[j], 0.f);
        float2 b = *(const float2*)&B[((lane << 2) + j) * 2];
        a0 = fmaf(v, b.x, a0);
        a1 = fmaf(v, b.y, a1);
    }
    for (int off = 32; off > 0; off >>= 1) {
        a0 += __shfl_down(a0, off, 64);
        a1 += __shfl_down(a1, off, 64);
    }
    if (lane == 0) {
        out[2 * m] = a0 + bias[0];
        out[2 * m + 1] = a1 + bias[1];
    }
}

extern "C" void kernel_launch(void* const* d_in, const int* in_sizes, int n_in,
                              void* d_out, int out_size, void* d_ws, size_t ws_size,
                              hipStream_t stream) {
    (void)in_sizes; (void)n_in; (void)out_size; (void)ws_size;
    const float* x_seq = (const float*)d_in[0];
    const int* ei = (const int*)d_in[1];
    const float* ews = (const float*)d_in[2];
    const float* h_enc_in = (const float*)d_in[3];
    const float* h_dec_in = (const float*)d_in[4];
    const float* encWx = (const float*)d_in[5];
    const float* encbx = (const float*)d_in[6];
    const float* encWh = (const float*)d_in[7];
    const float* encbh = (const float*)d_in[8];
    const float* elinW = (const float*)d_in[9];
    const float* elinb = (const float*)d_in[10];
    const float* decWx = (const float*)d_in[11];
    const float* decbx = (const float*)d_in[12];
    const float* decWh = (const float*)d_in[13];
    const float* decbh = (const float*)d_in[14];
    const float* dlinW = (const float*)d_in[15];
    const float* dlinb = (const float*)d_in[16];
    float* out = (float*)d_out;

    float* W = (float*)d_ws;
    float* h_enc = W; W += (size_t)NN * HE;
    float* h_dec = W; W += (size_t)NN * HE;
    float* aggx  = W; W += (size_t)NN * HE;
    float* aggh  = W; W += (size_t)NN * HE;
    float* hr    = W; W += (size_t)NN * HE;
    float* agghr = W; W += (size_t)NN * HE;
    float* gz    = W; W += (size_t)NN * HE;
    float* zlat  = W; W += (size_t)NN * LT;
    float* yhat  = W; W += (size_t)NN * FIN;
    float* deg   = W; W += NN;
    int*   cnt   = (int*)W; W += NN;
    float* dinv  = W; W += NN;
    float* csr_nrm = W; W += EE;
    unsigned short* Mb = (unsigned short*)W; W += (size_t)NN * NN / 2;
    float* pbuf  = W; W += (size_t)ZR_NZ * NN * 512;
    // bf16 operand buffers (hi/lo), float-count = elems/2
    unsigned short* HenH = (unsigned short*)W; W += (size_t)NN * HE / 2;
    unsigned short* HenL = (unsigned short*)W; W += (size_t)NN * HE / 2;
    unsigned short* HdeH = (unsigned short*)W; W += (size_t)NN * HE / 2;
    unsigned short* HdeL = (unsigned short*)W; W += (size_t)NN * HE / 2;
    unsigned short* agghH = (unsigned short*)W; W += (size_t)NN * HE / 2;
    unsigned short* agghL = (unsigned short*)W; W += (size_t)NN * HE / 2;
    unsigned short* agghrH = (unsigned short*)W; W += (size_t)NN * HE / 2;
    unsigned short* agghrL = (unsigned short*)W; W += (size_t)NN * HE / 2;
    unsigned short* hrH = (unsigned short*)W; W += (size_t)NN * HE / 2;
    unsigned short* hrL = (unsigned short*)W; W += (size_t)NN * HE / 2;
    unsigned short* rhH = (unsigned short*)W; W += (size_t)NN * HE / 2;
    unsigned short* rhL = (unsigned short*)W; W += (size_t)NN * HE / 2;
    unsigned short* zlatH = (unsigned short*)W; W += (size_t)NN * LT / 2;
    unsigned short* zlatL = (unsigned short*)W; W += (size_t)NN * LT / 2;
    unsigned short* aggxdH = (unsigned short*)W; W += (size_t)NN * LT / 2;
    unsigned short* aggxdL = (unsigned short*)W; W += (size_t)NN * LT / 2;
    unsigned short* WehT_h = (unsigned short*)W; W += (size_t)6 * HE * HE / 2;
    unsigned short* WehT_l = (unsigned short*)W; W += (size_t)6 * HE * HE / 2;
    unsigned short* WdhT_h = (unsigned short*)W; W += (size_t)6 * HE * HE / 2;
    unsigned short* WdhT_l = (unsigned short*)W; W += (size_t)6 * HE * HE / 2;
    unsigned short* WdxT_h = (unsigned short*)W; W += (size_t)6 * HE * LT / 2;
    unsigned short* WdxT_l = (unsigned short*)W; W += (size_t)6 * HE * LT / 2;
    unsigned short* elinT_h = (unsigned short*)W; W += (size_t)HE * LT / 2;
    unsigned short* elinT_l = (unsigned short*)W; W += (size_t)HE * LT / 2;
    int* roff = (int*)W;
    int* cur  = roff + (NN + 2);
    int* csr_src = cur + NN;

    // ---- one-time per-call prep ----
    k_tsplit<<<dim3(HE * HE / 256, 6), 256, 0, stream>>>(encWh, WehT_h, WehT_l, HE, HE);
    k_tsplit<<<dim3(HE * HE / 256, 6), 256, 0, stream>>>(decWh, WdhT_h, WdhT_l, HE, HE);
    k_tsplit<<<dim3(LT * HE / 256, 6), 256, 0, stream>>>(decWx, WdxT_h, WdxT_l, LT, HE);
    k_tsplit<<<dim3(HE * LT / 256, 1), 256, 0, stream>>>(elinW, elinT_h, elinT_l, HE, LT);
    k_cvt<<<NN * HE / 4 / 256, 256, 0, stream>>>(h_enc_in, HenH, HenL, NN * HE / 4);
    k_cvt<<<NN * HE / 4 / 256, 256, 0, stream>>>(h_dec_in, HdeH, HdeL, NN * HE / 4);
    hipMemcpyAsync(h_enc, h_enc_in, sizeof(float) * NN * HE, hipMemcpyDeviceToDevice, stream);
    hipMemcpyAsync(h_dec, h_dec_in, sizeof(float) * NN * HE, hipMemcpyDeviceToDevice, stream);

    const size_t WH = (size_t)HE * HE;      // Wh slice
    const size_t WX = (size_t)HE * LT;      // decWx transposed slice

    for (int step = 0; step < T_OBS + PREDN - 1; ++step) {
        bool sparse = step < T_OBS;
        const float* xin;
        if (sparse) {
            const int* srcp = ei + (size_t)step * 2 * EE;
            const int* dstp = srcp + EE;
            const float* ewt = ews + (size_t)step * EE;
            hipMemsetAsync(deg, 0, sizeof(float) * NN * 2, stream);
            k_degcnt<<<EE / 256, 256, 0, stream>>>(srcp, dstp, ewt, deg, cnt);
            k_scan<<<1, 256, 0, stream>>>(cnt, deg, roff, cur, dinv);
            k_scatter2<<<EE / 256, 256, 0, stream>>>(srcp, dstp, ewt, dinv, cur,
                                                     csr_src, csr_nrm);
            xin = x_seq + (size_t)step * NN * FIN;
        } else {
            k_ddeg<<<NN, 256, 0, stream>>>(yhat, dinv);
            k_dM<<<(NN * NN) / 256, 256, 0, stream>>>(yhat, dinv, Mb);
            xin = yhat;
        }

        // ======= encoder GRU =======
        if (sparse) k_spmm2<<<NN / 256, 256, 0, stream>>>(roff, csr_src, csr_nrm, xin, aggx);
        else        k_dmv2b<<<NN, 256, 0, stream>>>(Mb, xin, aggx);
        if (sparse) {
            k_spmm_v<HE><<<NN / 4, 256, 0, stream>>>(roff, csr_src, csr_nrm, h_enc,
                                                     aggh, agghH, agghL);
        } else {
            k_dmm_mf<HE><<<dim3(NN / 64, HE / 64, DMM_NZ), 256, 0, stream>>>(Mb, h_enc, pbuf);
            k_redks<HE, DMM_NZ><<<NN * HE / 4 / 256, 256, 0, stream>>>(pbuf, aggh, agghH, agghL);
        }
        {
            Seg4 sg = {};
            sg.s[0] = {HenH, HenL, WehT_h, WehT_l, HE, HE, HE, 2 * WH};
            sg.s[1] = {agghH, agghL, WehT_h + WH, WehT_l + WH, HE, HE, HE, 2 * WH};
            k_mf_ks<<<dim3(NN / 64, 8, ZR_NZ), 256, 0, stream>>>(sg, 2, 512, ZR_NZ, 1, 512, pbuf);
        }
        k_zr_ep<<<NN * 512 / 4 / 256, 256, 0, stream>>>(pbuf, encbx, encbh, h_enc,
                                                        xin, aggx, encWx, gz, hr, hrH, hrL);
        if (sparse) {
            k_spmm_v<HE><<<NN / 4, 256, 0, stream>>>(roff, csr_src, csr_nrm, hr,
                                                     agghr, agghrH, agghrL);
        } else {
            k_dmm_mf<HE><<<dim3(NN / 64, HE / 64, DMM_NZ), 256, 0, stream>>>(Mb, hr, pbuf);
            k_redks<HE, DMM_NZ><<<NN * HE / 4 / 256, 256, 0, stream>>>(pbuf, agghr, agghrH, agghrL);
        }
        {
            Seg4 sg = {};
            sg.s[0] = {hrH, hrL, WehT_h + 4 * WH, WehT_l + 4 * WH, HE, HE, HE, 0};
            sg.s[1] = {agghrH, agghrL, WehT_h + 5 * WH, WehT_l + 5 * WH, HE, HE, HE, 0};
            k_mf_ks<<<dim3(NN / 64, 4, GT_NZ), 256, 0, stream>>>(sg, 2, 512, GT_NZ, 0, HE, pbuf);
        }
        k_gt_ep<<<NN * HE / 4 / 256, 256, 0, stream>>>(pbuf, encbx + 2 * HE, encbh + 2 * HE,
                                                       gz, xin, aggx, encWx + 4 * FIN * HE,
                                                       h_enc, HenH, HenL, rhH, rhL);
        {
            Seg4 sg = {};
            sg.s[0] = {rhH, rhL, elinT_h, elinT_l, HE, HE, HE, 0};
            k_mf_ks<<<dim3(NN / 64, 2, LIN_NZ), 256, 0, stream>>>(sg, 1, 256, LIN_NZ, 0, LT, pbuf);
        }
        k_lin_ep<<<NN * LT / 4 / 256, 256, 0, stream>>>(pbuf, elinb, zlat, zlatH, zlatL);

        // ======= decoder GRU =======
        if (sparse) {
            k_spmm_v<LT><<<NN / 4, 256, 0, stream>>>(roff, csr_src, csr_nrm, zlat,
                                                     aggx, aggxdH, aggxdL);
        } else {
            k_dmm_mf<LT><<<dim3(NN / 64, LT / 64, DMM_NZ), 256, 0, stream>>>(Mb, zlat, pbuf);
            k_redks<LT, DMM_NZ><<<NN * LT / 4 / 256, 256, 0, stream>>>(pbuf, aggx, aggxdH, aggxdL);
        }
        if (sparse) {
            k_spmm_v<HE><<<NN / 4, 256, 0, stream>>>(roff, csr_src, csr_nrm, h_dec,
                                                     aggh, agghH, agghL);
        } else {
            k_dmm_mf<HE><<<dim3(NN / 64, HE / 64, DMM_NZ), 256, 0, stream>>>(Mb, h_dec, pbuf);
            k_redks<HE, DMM_NZ><<<NN * HE / 4 / 256, 256, 0, stream>>>(pbuf, aggh, agghH, agghL);
        }
        {
            Seg4 sg = {};
            sg.s[0] = {zlatH, zlatL, WdxT_h, WdxT_l, LT, LT, LT, 2 * WX};
            sg.s[1] = {aggxdH, aggxdL, WdxT_h + WX, WdxT_l + WX, LT, LT, LT, 2 * WX};
            sg.s[2] = {HdeH, HdeL, WdhT_h, WdhT_l, HE, HE, HE, 2 * WH};
            sg.s[3] = {agghH, agghL, WdhT_h + WH, WdhT_l + WH, HE, HE, HE, 2 * WH};
            k_mf_ks<<<dim3(NN / 64, 8, ZR_NZ), 256, 0, stream>>>(sg, 4, 768, ZR_NZ, 1, 512, pbuf);
        }
        k_zr_ep<<<NN * 512 / 4 / 256, 256, 0, stream>>>(pbuf, decbx, decbh, h_dec,
                                                        nullptr, nullptr, nullptr,
                                                        gz, hr, hrH, hrL);
        if (sparse) {
            k_spmm_v<HE><<<NN / 4, 256, 0, stream>>>(roff, csr_src, csr_nrm, hr,
                                                     agghr, agghrH, agghrL);
        } else {
            k_dmm_mf<HE><<<dim3(NN / 64, HE / 64, DMM_NZ), 256, 0, stream>>>(Mb, hr, pbuf);
            k_redks<HE, DMM_NZ><<<NN * HE / 4 / 256, 256, 0, stream>>>(pbuf, agghr, agghrH, agghrL);
        }
        {
            Seg4 sg = {};
            sg.s[0] = {zlatH, zlatL, WdxT_h + 4 * WX, WdxT_l + 4 * WX, LT, LT, LT, 0};
            sg.s[1] = {aggxdH, aggxdL, WdxT_h + 5 * WX, WdxT_l + 5 * WX, LT, LT, LT, 0};
            sg.s[2] = {hrH, hrL, WdhT_h + 4 * WH, WdhT_l + 4 * WH, HE, HE, HE, 0};
            sg.s[3] = {agghrH, agghrL, WdhT_h + 5 * WH, WdhT_l + 5 * WH, HE, HE, HE, 0};
            k_mf_ks<<<dim3(NN / 64, 4, GT_NZ), 256, 0, stream>>>(sg, 4, 768, GT_NZ, 0, HE, pbuf);
        }
        k_gt_ep<<<NN * HE / 4 / 256, 256, 0, stream>>>(pbuf, decbx + 2 * HE, decbh + 2 * HE,
                                                       gz, nullptr, nullptr, nullptr,
                                                       h_dec, HdeH, HdeL, nullptr, nullptr);
        k_declin<<<NN / 4, 256, 0, stream>>>(h_dec, dlinW, dlinb, yhat);

        if (step >= T_OBS - 1) {
            hipMemcpyAsync(out + (size_t)(step - (T_OBS - 1)) * NN * FIN, yhat,
                           sizeof(float) * NN * FIN, hipMemcpyDeviceToDevice, stream);
        }
    }
}

// Round 10
// 1742.051 us; speedup vs baseline: 1.1810x; 1.1810x over previous
//
#include <hip/hip_runtime.h>
#include <math.h>

#define NN 2048
#define EE 65536
#define T_OBS 6
#define FIN 2
#define HE 256
#define LT 128
#define PREDN 6
#define DMM_NZ 8
#define ZR_NZ 4
#define GT_NZ 8
#define LIN_NZ 8

typedef __attribute__((ext_vector_type(8))) short short8v;
typedef __attribute__((ext_vector_type(4))) float float4v;

static __device__ __forceinline__ unsigned short f2bf(float f) {
    union { float f; unsigned u; } v; v.f = f;
    unsigned r = v.u + 0x7fff + ((v.u >> 16) & 1);
    return (unsigned short)(r >> 16);
}

// truncation split: f ~= hi + lo, |err| <= 2^-16 |f|
static __device__ __forceinline__ void bfsplit(float f, unsigned short& h,
                                               unsigned short& l) {
    unsigned u = __float_as_uint(f);
    h = (unsigned short)(u >> 16);
    float hf = __uint_as_float(u & 0xffff0000u);
    l = (unsigned short)(__float_as_uint(f - hf) >> 16);
}

static __device__ __forceinline__ float bf2f(unsigned short b) {
    return __uint_as_float(((unsigned)b) << 16);
}

// ---------------- batched sparse graph prep (all T_OBS graphs upfront) ----------------
__global__ void k_degcnt_b(const int* __restrict__ ei, const float* __restrict__ ews,
                           float* __restrict__ deg_all, int* __restrict__ cnt_all) {
    int t = blockIdx.y;
    int e = blockIdx.x * blockDim.x + threadIdx.x;
    const int* src = ei + (size_t)t * 2 * EE;
    const int* dst = src + EE;
    const float* ew = ews + (size_t)t * EE;
    if (e < EE) {
        atomicAdd(&deg_all[t * NN + src[e]], ew[e]);
        atomicAdd(&cnt_all[t * NN + dst[e]], 1);
    }
}

// one block per graph: scan cnt -> roff/cur, dinv = rsqrt(deg)
__global__ void k_scan_b(const int* __restrict__ cnt_all, const float* __restrict__ deg_all,
                         int* __restrict__ roff_all, int* __restrict__ cur_all,
                         float* __restrict__ dinv_all) {
    __shared__ int part[256];
    int tg = blockIdx.x;
    const int* cnt = cnt_all + tg * NN;
    const float* deg = deg_all + tg * NN;
    int* roff = roff_all + tg * (NN + 1);
    int* cur = cur_all + tg * NN;
    float* dinv = dinv_all + tg * NN;
    int t = threadIdx.x;
#pragma unroll
    for (int i = t; i < NN; i += 256) {
        float d = deg[i];
        dinv[i] = d > 0.f ? 1.f / sqrtf(d) : 0.f;
    }
    int loc[8];
    int s = 0;
#pragma unroll
    for (int i = 0; i < 8; i++) { loc[i] = cnt[t * 8 + i]; s += loc[i]; }
    part[t] = s;
    __syncthreads();
    for (int off = 1; off < 256; off <<= 1) {
        int v = (t >= off) ? part[t - off] : 0;
        __syncthreads();
        part[t] += v;
        __syncthreads();
    }
    int run = (t == 0) ? 0 : part[t - 1];
#pragma unroll
    for (int i = 0; i < 8; i++) {
        int idx = t * 8 + i;
        roff[idx] = run;
        cur[idx] = run;
        run += loc[i];
    }
    if (t == 255) roff[NN] = run;
}

__global__ void k_scatter2_b(const int* __restrict__ ei, const float* __restrict__ ews,
                             const float* __restrict__ dinv_all, int* __restrict__ cur_all,
                             int* __restrict__ csr_src_all, float* __restrict__ csr_nrm_all) {
    int tg = blockIdx.y;
    int e = blockIdx.x * blockDim.x + threadIdx.x;
    const int* src = ei + (size_t)tg * 2 * EE;
    const int* dst = src + EE;
    const float* ew = ews + (size_t)tg * EE;
    const float* dinv = dinv_all + tg * NN;
    if (e < EE) {
        int s = src[e], d = dst[e];
        int p = atomicAdd(&cur_all[tg * NN + d], 1);
        csr_src_all[(size_t)tg * EE + p] = s;
        csr_nrm_all[(size_t)tg * EE + p] = -dinv[s] * ew[e] * dinv[d];
    }
}

// batched F=2 encoder x-aggregation (state-independent): all 6 steps upfront
__global__ void k_spmm2_b(const int* __restrict__ roff_all, const int* __restrict__ csr_src_all,
                          const float* __restrict__ csr_nrm_all, const float* __restrict__ x_seq,
                          float* __restrict__ aggx_all) {
    int tg = blockIdx.y;
    int nid = blockIdx.x * blockDim.x + threadIdx.x;
    if (nid < NN) {
        const int* roff = roff_all + tg * (NN + 1);
        const int* csr_src = csr_src_all + (size_t)tg * EE;
        const float* csr_nrm = csr_nrm_all + (size_t)tg * EE;
        const float* X = x_seq + (size_t)tg * NN * FIN;
        int s0 = roff[nid], s1 = roff[nid + 1];
        float a0 = 0.f, a1 = 0.f;
        for (int s = s0; s < s1; ++s) {
            int i = csr_src[s]; float w = csr_nrm[s];
            float2 xv = *(const float2*)&X[2 * i];
            a0 = fmaf(w, xv.x, a0);
            a1 = fmaf(w, xv.y, a1);
        }
        aggx_all[(size_t)tg * NN * FIN + 2 * nid] = a0;
        aggx_all[(size_t)tg * NN * FIN + 2 * nid + 1] = a1;
    }
}

// CSR SpMM, wave per node, float4 per lane, 8 edges batched
template <int F>
__global__ void k_spmm_v(const int* __restrict__ roff, const int* __restrict__ csr_src,
                         const float* __restrict__ csr_nrm,
                         const float* __restrict__ X, float* __restrict__ out) {
    int w = threadIdx.x >> 6, lane = threadIdx.x & 63;
    int nid = (blockIdx.x << 2) + w;
    int c = lane << 2;
    int s0 = roff[nid], s1 = roff[nid + 1];
    float4 acc = make_float4(0.f, 0.f, 0.f, 0.f);
    int s = s0;
    for (; s + 8 <= s1; s += 8) {
        int is[8]; float ws[8];
#pragma unroll
        for (int j = 0; j < 8; j++) { is[j] = csr_src[s + j]; ws[j] = csr_nrm[s + j]; }
        if (c < F) {
            float4 xv[8];
#pragma unroll
            for (int j = 0; j < 8; j++) xv[j] = *(const float4*)&X[(size_t)is[j] * F + c];
#pragma unroll
            for (int j = 0; j < 8; j++) {
                acc.x = fmaf(ws[j], xv[j].x, acc.x);
                acc.y = fmaf(ws[j], xv[j].y, acc.y);
                acc.z = fmaf(ws[j], xv[j].z, acc.z);
                acc.w = fmaf(ws[j], xv[j].w, acc.w);
            }
        }
    }
    for (; s < s1; ++s) {
        int i0 = csr_src[s]; float w0 = csr_nrm[s];
        if (c < F) {
            float4 xv = *(const float4*)&X[(size_t)i0 * F + c];
            acc.x = fmaf(w0, xv.x, acc.x);
            acc.y = fmaf(w0, xv.y, acc.y);
            acc.z = fmaf(w0, xv.z, acc.z);
            acc.w = fmaf(w0, xv.w, acc.w);
        }
    }
    if (c < F) *(float4*)&out[(size_t)nid * F + c] = acc;
}

// ---------------- dense graph prep (rollout) ----------------
__global__ void k_ddeg(const float* __restrict__ c, float* __restrict__ dinv) {
    int i = blockIdx.x;
    int t = threadIdx.x;
    float xi = c[2 * i], yi = c[2 * i + 1];
    float s = 0.f;
    for (int j = t; j < NN; j += 256) {
        float dx = xi - c[2 * j], dy = yi - c[2 * j + 1];
        float d = sqrtf(dx * dx + dy * dy);
        if (d > 0.f && d < 0.5f) s += 2.f * d;
    }
    __shared__ float red[256];
    red[t] = s;
    __syncthreads();
    for (int off = 128; off > 0; off >>= 1) {
        if (t < off) red[t] += red[t + off];
        __syncthreads();
    }
    if (t == 0) {
        float d = red[0];
        dinv[i] = d > 0.f ? 1.f / sqrtf(d) : 0.f;
    }
}

// bf16 M only
__global__ void k_dM(const float* __restrict__ c, const float* __restrict__ dinv,
                     unsigned short* __restrict__ Mb) {
    int idx = blockIdx.x * blockDim.x + threadIdx.x;
    int i = idx >> 11, j = idx & (NN - 1);
    float dx = c[2 * i] - c[2 * j], dy = c[2 * i + 1] - c[2 * j + 1];
    float d = sqrtf(dx * dx + dy * dy);
    float w = (d > 0.f && d < 0.5f) ? 2.f * d : 0.f;
    Mb[idx] = f2bf(-(dinv[i] * w) * dinv[j]);
}

// dense agg via bf16 MFMA
template <int F>
__global__ __launch_bounds__(256) void k_dmm_mf(
    const unsigned short* __restrict__ Mb, const float* __restrict__ X,
    float* __restrict__ pbuf)
{
    __shared__ __align__(16) unsigned short Ms[64][72];
    __shared__ __align__(16) unsigned short Xs[64][72];
    const int tid = threadIdx.x;
    const int wid = tid >> 6, lane = tid & 63;
    const int m0 = blockIdx.x << 6, n0 = blockIdx.y << 6;
    const int kb0 = blockIdx.z << 8;
    const int lr = lane & 15;
    const int kg = lane >> 4;
    float4v acc[4];
#pragma unroll
    for (int t = 0; t < 4; t++) acc[t] = (float4v){0.f, 0.f, 0.f, 0.f};

    for (int kb = kb0; kb < kb0 + 256; kb += 64) {
#pragma unroll
        for (int it = 0; it < 2; it++) {
            int i = tid + it * 256;
            int r = i >> 3, c8 = (i & 7) << 3;
            *(short8v*)&Ms[r][c8] =
                *(const short8v*)&Mb[(size_t)(m0 + r) * NN + kb + c8];
        }
#pragma unroll
        for (int it = 0; it < 2; it++) {
            int i = tid + it * 256;
            int k2 = (i & 31) << 1;
            int n4 = (i >> 5) << 2;
            float4 va = *(const float4*)&X[(size_t)(kb + k2) * F + n0 + n4];
            float4 vb = *(const float4*)&X[(size_t)(kb + k2 + 1) * F + n0 + n4];
            unsigned pk;
            pk = (unsigned)f2bf(va.x) | ((unsigned)f2bf(vb.x) << 16);
            *(unsigned*)&Xs[n4 + 0][k2] = pk;
            pk = (unsigned)f2bf(va.y) | ((unsigned)f2bf(vb.y) << 16);
            *(unsigned*)&Xs[n4 + 1][k2] = pk;
            pk = (unsigned)f2bf(va.z) | ((unsigned)f2bf(vb.z) << 16);
            *(unsigned*)&Xs[n4 + 2][k2] = pk;
            pk = (unsigned)f2bf(va.w) | ((unsigned)f2bf(vb.w) << 16);
            *(unsigned*)&Xs[n4 + 3][k2] = pk;
        }
        __syncthreads();
#pragma unroll
        for (int kh = 0; kh < 2; kh++) {
            int kk = kh * 32 + kg * 8;
            short8v a = *(const short8v*)&Ms[(wid << 4) + lr][kk];
#pragma unroll
            for (int t = 0; t < 4; t++) {
                short8v b = *(const short8v*)&Xs[(t << 4) + lr][kk];
                acc[t] = __builtin_amdgcn_mfma_f32_16x16x32_bf16(a, b, acc[t], 0, 0, 0);
            }
        }
        __syncthreads();
    }
    float* p = pbuf + (size_t)blockIdx.z * NN * F;
#pragma unroll
    for (int t = 0; t < 4; t++)
#pragma unroll
        for (int j = 0; j < 4; j++)
            p[(size_t)(m0 + (wid << 4) + (kg << 2) + j) * F + n0 + (t << 4) + lr] =
                acc[t][j];
}

template <int F, int NZ>
__global__ void k_redks(const float* __restrict__ pbuf, float* __restrict__ out) {
    const int TOT = NN * F / 4;
    int i = blockIdx.x * blockDim.x + threadIdx.x;
    if (i < TOT) {
        const float4* p = (const float4*)pbuf;
        float4 s = p[i];
#pragma unroll
        for (int z = 1; z < NZ; z++) {
            float4 v = p[(size_t)z * TOT + i];
            s.x += v.x; s.y += v.y; s.z += v.z; s.w += v.w;
        }
        ((float4*)out)[i] = s;
    }
}

// F=2 dense agg from bf16 M
__global__ void k_dmv2b(const unsigned short* __restrict__ Mb, const float* __restrict__ X,
                        float* __restrict__ out) {
    int i = blockIdx.x;
    int t = threadIdx.x;
    float a0 = 0.f, a1 = 0.f;
    for (int j = t; j < NN; j += 256) {
        float m = bf2f(Mb[(size_t)i * NN + j]);
        a0 = fmaf(m, X[2 * j], a0);
        a1 = fmaf(m, X[2 * j + 1], a1);
    }
    __shared__ float r0[256], r1[256];
    r0[t] = a0;
    r1[t] = a1;
    __syncthreads();
    for (int off = 128; off > 0; off >>= 1) {
        if (t < off) { r0[t] += r0[t + off]; r1[t] += r1[t + off]; }
        __syncthreads();
    }
    if (t == 0) { out[2 * i] = r0[0]; out[2 * i + 1] = r1[0]; }
}

// ---------------- bf16x3 MFMA GEMM segment core (r8 proven version) ----------------
template <bool RELU>
__device__ __forceinline__ void mfma_seg(
    unsigned short (*Ah)[40], unsigned short (*Al)[40],
    unsigned short (*Bh)[40], unsigned short (*Bl)[40],
    const float* __restrict__ A, int lda,
    const float* __restrict__ B, int ldb, int K,
    int m0, int tid, int wid, int lr, int kg, float4v (&acc)[4])
{
    for (int k0 = 0; k0 < K; k0 += 32) {
        {   // stage A: 64 rows x 32 k, hi/lo
            int r = tid >> 2, k8 = (tid & 3) << 3;
            const float* ap = &A[(size_t)(m0 + r) * lda + k0 + k8];
            float4 va = *(const float4*)ap;
            float4 vb = *(const float4*)(ap + 4);
            float v[8] = {va.x, va.y, va.z, va.w, vb.x, vb.y, vb.z, vb.w};
            short8v hv, lv;
#pragma unroll
            for (int j = 0; j < 8; j++) {
                float f = RELU ? fmaxf(v[j], 0.f) : v[j];
                unsigned short h, l;
                bfsplit(f, h, l);
                hv[j] = (short)h; lv[j] = (short)l;
            }
            *(short8v*)&Ah[r][k8] = hv;
            *(short8v*)&Al[r][k8] = lv;
        }
        {   // stage B transposed: 64 cols x 32 k, hi/lo
            int k2 = (tid & 15) << 1;
            int n4 = (tid >> 4) << 2;
            const float* bp = &B[(size_t)(k0 + k2) * ldb + n4];
            float4 va = *(const float4*)bp;
            float4 vb = *(const float4*)(bp + ldb);
            float v0[4] = {va.x, va.y, va.z, va.w};
            float v1[4] = {vb.x, vb.y, vb.z, vb.w};
#pragma unroll
            for (int j = 0; j < 4; j++) {
                unsigned short h0, l0, h1, l1;
                bfsplit(v0[j], h0, l0);
                bfsplit(v1[j], h1, l1);
                *(unsigned*)&Bh[n4 + j][k2] = (unsigned)h0 | ((unsigned)h1 << 16);
                *(unsigned*)&Bl[n4 + j][k2] = (unsigned)l0 | ((unsigned)l1 << 16);
            }
        }
        __syncthreads();
        short8v ah = *(short8v*)&Ah[(wid << 4) + lr][kg << 3];
        short8v al = *(short8v*)&Al[(wid << 4) + lr][kg << 3];
#pragma unroll
        for (int t = 0; t < 4; t++) {
            short8v bh = *(short8v*)&Bh[(t << 4) + lr][kg << 3];
            short8v bl = *(short8v*)&Bl[(t << 4) + lr][kg << 3];
            acc[t] = __builtin_amdgcn_mfma_f32_16x16x32_bf16(ah, bh, acc[t], 0, 0, 0);
            acc[t] = __builtin_amdgcn_mfma_f32_16x16x32_bf16(ah, bl, acc[t], 0, 0, 0);
            acc[t] = __builtin_amdgcn_mfma_f32_16x16x32_bf16(al, bh, acc[t], 0, 0, 0);
        }
        __syncthreads();
    }
}

// z/r gates K-split (MFMA). K01 = 0 (enc: x-parts in epilogue) or LT (dec).
__global__ __launch_bounds__(256) void k_zr_ks(
    const float* __restrict__ A0, int K01, const float* __restrict__ A1,
    const float* __restrict__ H, const float* __restrict__ A3,
    const float* __restrict__ Wx, const float* __restrict__ Wh,
    float* __restrict__ pbuf)
{
    __shared__ __align__(16) unsigned short Ah[64][40], Al[64][40],
                                            Bh[64][40], Bl[64][40];
    int tid = threadIdx.x;
    int wid = tid >> 6, lane = tid & 63, lr = lane & 15, kg = lane >> 4;
    int m0 = blockIdx.x << 6;
    int g = blockIdx.y >> 2;
    int n0 = (blockIdx.y & 3) << 6;
    float4v acc[4];
#pragma unroll
    for (int t = 0; t < 4; t++) acc[t] = (float4v){0.f, 0.f, 0.f, 0.f};
    const float* As[4] = {A0, A1, H, A3};
    const int ldas[4] = {K01, K01, HE, HE};
    const float* Bs[4] = {
        Wx + (size_t)(g * 2 + 0) * K01 * HE + n0,
        Wx + (size_t)(g * 2 + 1) * K01 * HE + n0,
        Wh + (size_t)(g * 2 + 0) * HE * HE + n0,
        Wh + (size_t)(g * 2 + 1) * HE * HE + n0};
    const int Ks[4] = {K01, K01, HE, HE};
    int chunk = (2 * K01 + 2 * HE) / ZR_NZ;
    int lo = blockIdx.z * chunk, hi = lo + chunk;
    int off = 0;
#pragma unroll
    for (int s = 0; s < 4; s++) {
        int a = lo - off; a = a < 0 ? 0 : a;
        int b = hi - off; b = b > Ks[s] ? Ks[s] : b;
        if (b > a)
            mfma_seg<false>(Ah, Al, Bh, Bl, As[s] + a, ldas[s],
                            Bs[s] + (size_t)a * HE, HE, b - a,
                            m0, tid, wid, lr, kg, acc);
        off += Ks[s];
    }
    float* p = pbuf + (size_t)blockIdx.z * NN * 512;
    int cbase = (g << 8) + n0;
#pragma unroll
    for (int t = 0; t < 4; t++)
#pragma unroll
        for (int j = 0; j < 4; j++)
            p[(size_t)(m0 + (wid << 4) + (kg << 2) + j) * 512 + cbase + (t << 4) + lr] =
                acc[t][j];
}

// epilogue: + rank-2 (x,aggx) terms when Wx != nullptr (encoder)
__global__ void k_zr_ep(const float* __restrict__ pbuf,
                        const float* __restrict__ bx, const float* __restrict__ bh,
                        const float* __restrict__ H,
                        const float* __restrict__ x2, const float* __restrict__ ax2,
                        const float* __restrict__ Wx,
                        float* __restrict__ gz, float* __restrict__ hr)
{
    int i = blockIdx.x * 256 + threadIdx.x;  // < NN*512/4
    const float4* p = (const float4*)pbuf;
    const size_t S = (size_t)NN * 512 / 4;
    float4 a = p[i];
#pragma unroll
    for (int z = 1; z < ZR_NZ; z++) {
        float4 v = p[(size_t)z * S + i];
        a.x += v.x; a.y += v.y; a.z += v.z; a.w += v.w;
    }
    int row = i >> 7, c = (i & 127) << 2;
    int g = c >> 8, cc = c & 255;
    if (Wx) {
        float x0 = x2[2 * row], x1 = x2[2 * row + 1];
        float q0 = ax2[2 * row], q1 = ax2[2 * row + 1];
        const float* W0 = Wx + (size_t)(g * 2 + 0) * FIN * HE;
        const float* W1 = Wx + (size_t)(g * 2 + 1) * FIN * HE;
        float4 w00 = *(const float4*)&W0[cc];
        float4 w01 = *(const float4*)&W0[HE + cc];
        float4 w10 = *(const float4*)&W1[cc];
        float4 w11 = *(const float4*)&W1[HE + cc];
        a.x += x0 * w00.x + x1 * w01.x + q0 * w10.x + q1 * w11.x;
        a.y += x0 * w00.y + x1 * w01.y + q0 * w10.y + q1 * w11.y;
        a.z += x0 * w00.z + x1 * w01.z + q0 * w10.z + q1 * w11.z;
        a.w += x0 * w00.w + x1 * w01.w + q0 * w10.w + q1 * w11.w;
    }
    float4 b0 = *(const float4*)&bx[c];
    float4 b1 = *(const float4*)&bh[c];
    float4 s;
    s.x = 1.f / (1.f + expf(-(a.x + b0.x + b1.x)));
    s.y = 1.f / (1.f + expf(-(a.y + b0.y + b1.y)));
    s.z = 1.f / (1.f + expf(-(a.z + b0.z + b1.z)));
    s.w = 1.f / (1.f + expf(-(a.w + b0.w + b1.w)));
    if (c < HE) {
        *(float4*)&gz[(size_t)row * HE + c] = s;
    } else {
        float4 h = *(const float4*)&H[(size_t)row * HE + cc];
        s.x *= h.x; s.y *= h.y; s.z *= h.z; s.w *= h.w;
        *(float4*)&hr[(size_t)row * HE + cc] = s;
    }
}

// candidate gate K-split (MFMA)
__global__ __launch_bounds__(256) void k_gt_ks(
    const float* __restrict__ A0, int K01, const float* __restrict__ A1,
    const float* __restrict__ hr, const float* __restrict__ A3,
    const float* __restrict__ Wx2, const float* __restrict__ Wh2,
    float* __restrict__ pbuf)
{
    __shared__ __align__(16) unsigned short Ah[64][40], Al[64][40],
                                            Bh[64][40], Bl[64][40];
    int tid = threadIdx.x;
    int wid = tid >> 6, lane = tid & 63, lr = lane & 15, kg = lane >> 4;
    int m0 = blockIdx.x << 6;
    int n0 = blockIdx.y << 6;
    float4v acc[4];
#pragma unroll
    for (int t = 0; t < 4; t++) acc[t] = (float4v){0.f, 0.f, 0.f, 0.f};
    const float* As[4] = {A0, A1, hr, A3};
    const int ldas[4] = {K01, K01, HE, HE};
    const float* Bs[4] = {
        Wx2 + n0,
        Wx2 + (size_t)K01 * HE + n0,
        Wh2 + n0,
        Wh2 + (size_t)HE * HE + n0};
    const int Ks[4] = {K01, K01, HE, HE};
    int chunk = (2 * K01 + 2 * HE) / GT_NZ;
    int lo = blockIdx.z * chunk, hi = lo + chunk;
    int off = 0;
#pragma unroll
    for (int s = 0; s < 4; s++) {
        int a = lo - off; a = a < 0 ? 0 : a;
        int b = hi - off; b = b > Ks[s] ? Ks[s] : b;
        if (b > a)
            mfma_seg<false>(Ah, Al, Bh, Bl, As[s] + a, ldas[s],
                            Bs[s] + (size_t)a * HE, HE, b - a,
                            m0, tid, wid, lr, kg, acc);
        off += Ks[s];
    }
    float* p = pbuf + (size_t)blockIdx.z * NN * HE;
#pragma unroll
    for (int t = 0; t < 4; t++)
#pragma unroll
        for (int j = 0; j < 4; j++)
            p[(size_t)(m0 + (wid << 4) + (kg << 2) + j) * HE + n0 + (t << 4) + lr] =
                acc[t][j];
}

// epilogue: H = z*H + (1-z)*tanh(sum + rank2 + b)
__global__ void k_gt_ep(const float* __restrict__ pbuf,
                        const float* __restrict__ bx2, const float* __restrict__ bh2,
                        const float* __restrict__ gz,
                        const float* __restrict__ x2, const float* __restrict__ ax2,
                        const float* __restrict__ Wx2,
                        float* __restrict__ H)
{
    int i = blockIdx.x * 256 + threadIdx.x;  // < NN*256/4
    const float4* p = (const float4*)pbuf;
    const size_t S = (size_t)NN * HE / 4;
    float4 a = p[i];
#pragma unroll
    for (int z = 1; z < GT_NZ; z++) {
        float4 v = p[(size_t)z * S + i];
        a.x += v.x; a.y += v.y; a.z += v.z; a.w += v.w;
    }
    int row = i >> 6, c = (i & 63) << 2;
    if (Wx2) {
        float x0 = x2[2 * row], x1 = x2[2 * row + 1];
        float q0 = ax2[2 * row], q1 = ax2[2 * row + 1];
        float4 w00 = *(const float4*)&Wx2[c];
        float4 w01 = *(const float4*)&Wx2[HE + c];
        float4 w10 = *(const float4*)&Wx2[2 * HE + c];
        float4 w11 = *(const float4*)&Wx2[3 * HE + c];
        a.x += x0 * w00.x + x1 * w01.x + q0 * w10.x + q1 * w11.x;
        a.y += x0 * w00.y + x1 * w01.y + q0 * w10.y + q1 * w11.y;
        a.z += x0 * w00.z + x1 * w01.z + q0 * w10.z + q1 * w11.z;
        a.w += x0 * w00.w + x1 * w01.w + q0 * w10.w + q1 * w11.w;
    }
    float4 b0 = *(const float4*)&bx2[c];
    float4 b1 = *(const float4*)&bh2[c];
    size_t idx = (size_t)row * HE + c;
    float4 z = *(const float4*)&gz[idx];
    float4 h = *(const float4*)&H[idx];
    float4 o;
    o.x = z.x * h.x + (1.f - z.x) * tanhf(a.x + b0.x + b1.x);
    o.y = z.y * h.y + (1.f - z.y) * tanhf(a.y + b0.y + b1.y);
    o.z = z.z * h.z + (1.f - z.z) * tanhf(a.z + b0.z + b1.z);
    o.w = z.w * h.w + (1.f - z.w) * tanhf(a.w + b0.w + b1.w);
    *(float4*)&H[idx] = o;
}

// latent linear K-split (MFMA, relu on A)
__global__ __launch_bounds__(256) void k_lin_ks(
    const float* __restrict__ A, const float* __restrict__ B,
    float* __restrict__ pbuf)
{
    __shared__ __align__(16) unsigned short Ah[64][40], Al[64][40],
                                            Bh[64][40], Bl[64][40];
    int tid = threadIdx.x;
    int wid = tid >> 6, lane = tid & 63, lr = lane & 15, kg = lane >> 4;
    int m0 = blockIdx.x << 6;
    int n0 = blockIdx.y << 6;
    int lo = blockIdx.z << 5;  // 32 per slice
    float4v acc[4];
#pragma unroll
    for (int t = 0; t < 4; t++) acc[t] = (float4v){0.f, 0.f, 0.f, 0.f};
    mfma_seg<true>(Ah, Al, Bh, Bl, A + lo, HE, B + (size_t)lo * LT + n0, LT, 32,
                   m0, tid, wid, lr, kg, acc);
    float* p = pbuf + (size_t)blockIdx.z * NN * LT;
#pragma unroll
    for (int t = 0; t < 4; t++)
#pragma unroll
        for (int j = 0; j < 4; j++)
            p[(size_t)(m0 + (wid << 4) + (kg << 2) + j) * LT + n0 + (t << 4) + lr] =
                acc[t][j];
}

__global__ void k_lin_ep(const float* __restrict__ pbuf,
                         const float* __restrict__ bias, float* __restrict__ out)
{
    int i = blockIdx.x * 256 + threadIdx.x;  // < NN*128/4
    const float4* p = (const float4*)pbuf;
    const size_t S = (size_t)NN * LT / 4;
    int c = (i & 31) << 2;
    float4 bb = *(const float4*)&bias[c];
    float4 s = make_float4(bb.x, bb.y, bb.z, bb.w);
#pragma unroll
    for (int z = 0; z < LIN_NZ; z++) {
        float4 v = p[z * S + i];
        s.x += v.x; s.y += v.y; s.z += v.z; s.w += v.w;
    }
    ((float4*)out)[i] = s;
}

// y_hat = relu(H) @ dlinW + dlinb : one wave per row
__global__ void k_declin(const float* __restrict__ A, const float* __restrict__ B,
                         const float* __restrict__ bias, float* __restrict__ out) {
    int w = threadIdx.x >> 6, lane = threadIdx.x & 63;
    int m = blockIdx.x * 4 + w;
    float4 a = *(const float4*)&A[(size_t)m * HE + (lane << 2)];
    float av[4] = {a.x, a.y, a.z, a.w};
    float a0 = 0.f, a1 = 0.f;
#pragma unroll
    for (int j = 0; j < 4; j++) {
        float v = fmaxf(av[j], 0.f);
        float2 b = *(const float2*)&B[((lane << 2) + j) * 2];
        a0 = fmaf(v, b.x, a0);
        a1 = fmaf(v, b.y, a1);
    }
    for (int off = 32; off > 0; off >>= 1) {
        a0 += __shfl_down(a0, off, 64);
        a1 += __shfl_down(a1, off, 64);
    }
    if (lane == 0) {
        out[2 * m] = a0 + bias[0];
        out[2 * m + 1] = a1 + bias[1];
    }
}

extern "C" void kernel_launch(void* const* d_in, const int* in_sizes, int n_in,
                              void* d_out, int out_size, void* d_ws, size_t ws_size,
                              hipStream_t stream) {
    (void)in_sizes; (void)n_in; (void)out_size; (void)ws_size;
    const float* x_seq = (const float*)d_in[0];
    const int* ei = (const int*)d_in[1];
    const float* ews = (const float*)d_in[2];
    const float* h_enc_in = (const float*)d_in[3];
    const float* h_dec_in = (const float*)d_in[4];
    const float* encWx = (const float*)d_in[5];
    const float* encbx = (const float*)d_in[6];
    const float* encWh = (const float*)d_in[7];
    const float* encbh = (const float*)d_in[8];
    const float* elinW = (const float*)d_in[9];
    const float* elinb = (const float*)d_in[10];
    const float* decWx = (const float*)d_in[11];
    const float* decbx = (const float*)d_in[12];
    const float* decWh = (const float*)d_in[13];
    const float* decbh = (const float*)d_in[14];
    const float* dlinW = (const float*)d_in[15];
    const float* dlinb = (const float*)d_in[16];
    float* out = (float*)d_out;

    float* W = (float*)d_ws;
    float* h_enc = W; W += (size_t)NN * HE;
    float* h_dec = W; W += (size_t)NN * HE;
    float* aggx  = W; W += (size_t)NN * HE;   // dense-step x agg scratch
    float* aggh  = W; W += (size_t)NN * HE;
    float* hr    = W; W += (size_t)NN * HE;
    float* agghr = W; W += (size_t)NN * HE;
    float* gz    = W; W += (size_t)NN * HE;
    float* zlat  = W; W += (size_t)NN * LT;
    float* yhat  = W; W += (size_t)NN * FIN;
    float* dinv_d = W; W += NN;               // dense-step dinv
    unsigned short* Mb = (unsigned short*)W; W += (size_t)NN * NN / 2;
    float* pbuf  = W; W += (size_t)ZR_NZ * NN * 512;
    // batched sparse-graph structures
    float* deg_all = W; W += (size_t)T_OBS * NN;
    int*   cnt_all = (int*)W; W += (size_t)T_OBS * NN;
    float* dinv_all = W; W += (size_t)T_OBS * NN;
    float* csr_nrm_all = W; W += (size_t)T_OBS * EE;
    float* aggx_all = W; W += (size_t)T_OBS * NN * FIN;
    int* roff_all = (int*)W; W += (size_t)T_OBS * (NN + 1) + 1;
    int* cur_all = (int*)W; W += (size_t)T_OBS * NN;
    int* csr_src_all = (int*)W; W += (size_t)T_OBS * EE;

    // ---- batched sparse prep (state-independent, off the critical chain) ----
    hipMemsetAsync(deg_all, 0, sizeof(float) * T_OBS * NN * 2, stream);  // deg+cnt
    k_degcnt_b<<<dim3(EE / 256, T_OBS), 256, 0, stream>>>(ei, ews, deg_all, cnt_all);
    k_scan_b<<<T_OBS, 256, 0, stream>>>(cnt_all, deg_all, roff_all, cur_all, dinv_all);
    k_scatter2_b<<<dim3(EE / 256, T_OBS), 256, 0, stream>>>(ei, ews, dinv_all, cur_all,
                                                            csr_src_all, csr_nrm_all);
    k_spmm2_b<<<dim3(NN / 256, T_OBS), 256, 0, stream>>>(roff_all, csr_src_all,
                                                         csr_nrm_all, x_seq, aggx_all);

    hipMemcpyAsync(h_enc, h_enc_in, sizeof(float) * NN * HE, hipMemcpyDeviceToDevice, stream);
    hipMemcpyAsync(h_dec, h_dec_in, sizeof(float) * NN * HE, hipMemcpyDeviceToDevice, stream);

    for (int step = 0; step < T_OBS + PREDN - 1; ++step) {
        bool sparse = step < T_OBS;
        const float* xin;
        const float* aggx_s;
        const int* roff = roff_all + step * (NN + 1);
        const int* csr_src = csr_src_all + (size_t)step * EE;
        const float* csr_nrm = csr_nrm_all + (size_t)step * EE;
        if (sparse) {
            xin = x_seq + (size_t)step * NN * FIN;
            aggx_s = aggx_all + (size_t)step * NN * FIN;
        } else {
            k_ddeg<<<NN, 256, 0, stream>>>(yhat, dinv_d);
            k_dM<<<(NN * NN) / 256, 256, 0, stream>>>(yhat, dinv_d, Mb);
            xin = yhat;
            k_dmv2b<<<NN, 256, 0, stream>>>(Mb, yhat, aggx);
            aggx_s = aggx;
        }

        // ======= encoder GRU (x: F=2 via rank-2 epilogue, H: h_enc) =======
        if (sparse) {
            k_spmm_v<HE><<<NN / 4, 256, 0, stream>>>(roff, csr_src, csr_nrm, h_enc, aggh);
        } else {
            k_dmm_mf<HE><<<dim3(NN / 64, HE / 64, DMM_NZ), 256, 0, stream>>>(Mb, h_enc, pbuf);
            k_redks<HE, DMM_NZ><<<NN * HE / 4 / 256, 256, 0, stream>>>(pbuf, aggh);
        }
        k_zr_ks<<<dim3(NN / 64, 8, ZR_NZ), 256, 0, stream>>>(xin, 0, aggx_s, h_enc, aggh,
                                                             encWx, encWh, pbuf);
        k_zr_ep<<<NN * 512 / 4 / 256, 256, 0, stream>>>(pbuf, encbx, encbh, h_enc,
                                                        xin, aggx_s, encWx, gz, hr);
        if (sparse) {
            k_spmm_v<HE><<<NN / 4, 256, 0, stream>>>(roff, csr_src, csr_nrm, hr, agghr);
        } else {
            k_dmm_mf<HE><<<dim3(NN / 64, HE / 64, DMM_NZ), 256, 0, stream>>>(Mb, hr, pbuf);
            k_redks<HE, DMM_NZ><<<NN * HE / 4 / 256, 256, 0, stream>>>(pbuf, agghr);
        }
        k_gt_ks<<<dim3(NN / 64, 4, GT_NZ), 256, 0, stream>>>(xin, 0, aggx_s, hr, agghr,
                                                             encWx + 4 * FIN * HE,
                                                             encWh + 4 * HE * HE, pbuf);
        k_gt_ep<<<NN * HE / 4 / 256, 256, 0, stream>>>(pbuf, encbx + 2 * HE,
                                                       encbh + 2 * HE, gz,
                                                       xin, aggx_s, encWx + 4 * FIN * HE,
                                                       h_enc);
        k_lin_ks<<<dim3(NN / 64, 2, LIN_NZ), 256, 0, stream>>>(h_enc, elinW, pbuf);
        k_lin_ep<<<NN * LT / 4 / 256, 256, 0, stream>>>(pbuf, elinb, zlat);

        // ======= decoder GRU (x: zlat F=128, H: h_dec) =======
        if (sparse) {
            k_spmm_v<LT><<<NN / 4, 256, 0, stream>>>(roff, csr_src, csr_nrm, zlat, aggx);
        } else {
            k_dmm_mf<LT><<<dim3(NN / 64, LT / 64, DMM_NZ), 256, 0, stream>>>(Mb, zlat, pbuf);
            k_redks<LT, DMM_NZ><<<NN * LT / 4 / 256, 256, 0, stream>>>(pbuf, aggx);
        }
        if (sparse) {
            k_spmm_v<HE><<<NN / 4, 256, 0, stream>>>(roff, csr_src, csr_nrm, h_dec, aggh);
        } else {
            k_dmm_mf<HE><<<dim3(NN / 64, HE / 64, DMM_NZ), 256, 0, stream>>>(Mb, h_dec, pbuf);
            k_redks<HE, DMM_NZ><<<NN * HE / 4 / 256, 256, 0, stream>>>(pbuf, aggh);
        }
        k_zr_ks<<<dim3(NN / 64, 8, ZR_NZ), 256, 0, stream>>>(zlat, LT, aggx, h_dec, aggh,
                                                             decWx, decWh, pbuf);
        k_zr_ep<<<NN * 512 / 4 / 256, 256, 0, stream>>>(pbuf, decbx, decbh, h_dec,
                                                        nullptr, nullptr, nullptr, gz, hr);
        if (sparse) {
            k_spmm_v<HE><<<NN / 4, 256, 0, stream>>>(roff, csr_src, csr_nrm, hr, agghr);
        } else {
            k_dmm_mf<HE><<<dim3(NN / 64, HE / 64, DMM_NZ), 256, 0, stream>>>(Mb, hr, pbuf);
            k_redks<HE, DMM_NZ><<<NN * HE / 4 / 256, 256, 0, stream>>>(pbuf, agghr);
        }
        k_gt_ks<<<dim3(NN / 64, 4, GT_NZ), 256, 0, stream>>>(zlat, LT, aggx, hr, agghr,
                                                             decWx + 4 * LT * HE,
                                                             decWh + 4 * HE * HE, pbuf);
        k_gt_ep<<<NN * HE / 4 / 256, 256, 0, stream>>>(pbuf, decbx + 2 * HE,
                                                       decbh + 2 * HE, gz,
                                                       nullptr, nullptr, nullptr,
                                                       h_dec);
        k_declin<<<NN / 4, 256, 0, stream>>>(h_dec, dlinW, dlinb, yhat);

        if (step >= T_OBS - 1) {
            hipMemcpyAsync(out + (size_t)(step - (T_OBS - 1)) * NN * FIN, yhat,
                           sizeof(float) * NN * FIN, hipMemcpyDeviceToDevice, stream);
        }
    }
}

// Round 11
// 1655.241 us; speedup vs baseline: 1.2429x; 1.0524x over previous
//
#include <hip/hip_runtime.h>
#include <math.h>

#define NN 2048
#define EE 65536
#define T_OBS 6
#define FIN 2
#define HE 256
#define LT 128
#define XC 384          // xcat width: [zlat(128) | h_dec(256)]
#define PREDN 6
#define DMM_NZ 8
#define ZR_NZ 4
#define GT_NZ 8
#define LIN_NZ 8

typedef __attribute__((ext_vector_type(8))) short short8v;
typedef __attribute__((ext_vector_type(4))) short short4v;
typedef __attribute__((ext_vector_type(4))) float float4v;

static __device__ __forceinline__ unsigned short f2bf(float f) {
    union { float f; unsigned u; } v; v.f = f;
    unsigned r = v.u + 0x7fff + ((v.u >> 16) & 1);
    return (unsigned short)(r >> 16);
}

static __device__ __forceinline__ void bfsplit(float f, unsigned short& h,
                                               unsigned short& l) {
    unsigned u = __float_as_uint(f);
    h = (unsigned short)(u >> 16);
    float hf = __uint_as_float(u & 0xffff0000u);
    l = (unsigned short)(__float_as_uint(f - hf) >> 16);
}

static __device__ __forceinline__ float bf2f(unsigned short b) {
    return __uint_as_float(((unsigned)b) << 16);
}

// ---------------- batched sparse graph prep ----------------
// LDS-binned histogram: 8 blocks per graph, flush per-bin partials.
__global__ void k_degcnt_lds(const int* __restrict__ ei, const float* __restrict__ ews,
                             float* __restrict__ deg_all, int* __restrict__ cnt_all) {
    __shared__ float ldeg[NN];
    __shared__ int lcnt[NN];
    int tg = blockIdx.y;
    const int* src = ei + (size_t)tg * 2 * EE;
    const int* dst = src + EE;
    const float* ew = ews + (size_t)tg * EE;
    for (int i = threadIdx.x; i < NN; i += 256) { ldeg[i] = 0.f; lcnt[i] = 0; }
    __syncthreads();
    const int EPB = EE / 8;
    int e0 = blockIdx.x * EPB;
    for (int e = e0 + threadIdx.x; e < e0 + EPB; e += 256) {
        atomicAdd(&ldeg[src[e]], ew[e]);
        atomicAdd(&lcnt[dst[e]], 1);
    }
    __syncthreads();
    for (int i = threadIdx.x; i < NN; i += 256) {
        float d = ldeg[i]; int cc = lcnt[i];
        if (d != 0.f) atomicAdd(&deg_all[tg * NN + i], d);
        if (cc) atomicAdd(&cnt_all[tg * NN + i], cc);
    }
}

__global__ void k_scan_b(const int* __restrict__ cnt_all, const float* __restrict__ deg_all,
                         int* __restrict__ roff_all, int* __restrict__ cur_all,
                         float* __restrict__ dinv_all) {
    __shared__ int part[256];
    int tg = blockIdx.x;
    const int* cnt = cnt_all + tg * NN;
    const float* deg = deg_all + tg * NN;
    int* roff = roff_all + tg * (NN + 1);
    int* cur = cur_all + tg * NN;
    float* dinv = dinv_all + tg * NN;
    int t = threadIdx.x;
#pragma unroll
    for (int i = t; i < NN; i += 256) {
        float d = deg[i];
        dinv[i] = d > 0.f ? 1.f / sqrtf(d) : 0.f;
    }
    int loc[8];
    int s = 0;
#pragma unroll
    for (int i = 0; i < 8; i++) { loc[i] = cnt[t * 8 + i]; s += loc[i]; }
    part[t] = s;
    __syncthreads();
    for (int off = 1; off < 256; off <<= 1) {
        int v = (t >= off) ? part[t - off] : 0;
        __syncthreads();
        part[t] += v;
        __syncthreads();
    }
    int run = (t == 0) ? 0 : part[t - 1];
#pragma unroll
    for (int i = 0; i < 8; i++) {
        int idx = t * 8 + i;
        roff[idx] = run;
        cur[idx] = run;
        run += loc[i];
    }
    if (t == 255) roff[NN] = run;
}

__global__ void k_scatter2_b(const int* __restrict__ ei, const float* __restrict__ ews,
                             const float* __restrict__ dinv_all, int* __restrict__ cur_all,
                             int* __restrict__ csr_src_all, float* __restrict__ csr_nrm_all) {
    int tg = blockIdx.y;
    int e = blockIdx.x * blockDim.x + threadIdx.x;
    const int* src = ei + (size_t)tg * 2 * EE;
    const int* dst = src + EE;
    const float* ew = ews + (size_t)tg * EE;
    const float* dinv = dinv_all + tg * NN;
    if (e < EE) {
        int s = src[e], d = dst[e];
        int p = atomicAdd(&cur_all[tg * NN + d], 1);
        csr_src_all[(size_t)tg * EE + p] = s;
        csr_nrm_all[(size_t)tg * EE + p] = -dinv[s] * ew[e] * dinv[d];
    }
}

__global__ void k_spmm2_b(const int* __restrict__ roff_all, const int* __restrict__ csr_src_all,
                          const float* __restrict__ csr_nrm_all, const float* __restrict__ x_seq,
                          float* __restrict__ aggx_all) {
    int tg = blockIdx.y;
    int nid = blockIdx.x * blockDim.x + threadIdx.x;
    if (nid < NN) {
        const int* roff = roff_all + tg * (NN + 1);
        const int* csr_src = csr_src_all + (size_t)tg * EE;
        const float* csr_nrm = csr_nrm_all + (size_t)tg * EE;
        const float* X = x_seq + (size_t)tg * NN * FIN;
        int s0 = roff[nid], s1 = roff[nid + 1];
        float a0 = 0.f, a1 = 0.f;
        for (int s = s0; s < s1; ++s) {
            int i = csr_src[s]; float w = csr_nrm[s];
            float2 xv = *(const float2*)&X[2 * i];
            a0 = fmaf(w, xv.x, a0);
            a1 = fmaf(w, xv.y, a1);
        }
        aggx_all[(size_t)tg * NN * FIN + 2 * nid] = a0;
        aggx_all[(size_t)tg * NN * FIN + 2 * nid + 1] = a1;
    }
}

// CSR SpMM gathering bf16 X; TPN threads per node; out stride ldo
template <int F, int TPN>
__global__ void k_spmm_vb(const int* __restrict__ roff, const int* __restrict__ csr_src,
                          const float* __restrict__ csr_nrm,
                          const unsigned short* __restrict__ Xb,
                          float* __restrict__ out, int ldo) {
    const int NPB = 256 / TPN;
    int w = threadIdx.x / TPN, l = threadIdx.x % TPN;
    int nid = blockIdx.x * NPB + w;
    int c = l << 2;
    int s0 = roff[nid], s1 = roff[nid + 1];
    float4 acc = make_float4(0.f, 0.f, 0.f, 0.f);
    int s = s0;
    for (; s + 8 <= s1; s += 8) {
        int is[8]; float ws[8];
#pragma unroll
        for (int j = 0; j < 8; j++) { is[j] = csr_src[s + j]; ws[j] = csr_nrm[s + j]; }
        if (c < F) {
            short4v xv[8];
#pragma unroll
            for (int j = 0; j < 8; j++)
                xv[j] = *(const short4v*)&Xb[(size_t)is[j] * F + c];
#pragma unroll
            for (int j = 0; j < 8; j++) {
                acc.x = fmaf(ws[j], bf2f((unsigned short)xv[j][0]), acc.x);
                acc.y = fmaf(ws[j], bf2f((unsigned short)xv[j][1]), acc.y);
                acc.z = fmaf(ws[j], bf2f((unsigned short)xv[j][2]), acc.z);
                acc.w = fmaf(ws[j], bf2f((unsigned short)xv[j][3]), acc.w);
            }
        }
    }
    for (; s < s1; ++s) {
        int i0 = csr_src[s]; float w0 = csr_nrm[s];
        if (c < F) {
            short4v xv = *(const short4v*)&Xb[(size_t)i0 * F + c];
            acc.x = fmaf(w0, bf2f((unsigned short)xv[0]), acc.x);
            acc.y = fmaf(w0, bf2f((unsigned short)xv[1]), acc.y);
            acc.z = fmaf(w0, bf2f((unsigned short)xv[2]), acc.z);
            acc.w = fmaf(w0, bf2f((unsigned short)xv[3]), acc.w);
        }
    }
    if (c < F) *(float4*)&out[(size_t)nid * ldo + c] = acc;
}

// ---------------- dense graph prep (rollout) ----------------
__global__ void k_ddeg(const float* __restrict__ c, float* __restrict__ dinv) {
    int i = blockIdx.x;
    int t = threadIdx.x;
    float xi = c[2 * i], yi = c[2 * i + 1];
    float s = 0.f;
    for (int j = t; j < NN; j += 256) {
        float dx = xi - c[2 * j], dy = yi - c[2 * j + 1];
        float d = sqrtf(dx * dx + dy * dy);
        if (d > 0.f && d < 0.5f) s += 2.f * d;
    }
    __shared__ float red[256];
    red[t] = s;
    __syncthreads();
    for (int off = 128; off > 0; off >>= 1) {
        if (t < off) red[t] += red[t + off];
        __syncthreads();
    }
    if (t == 0) {
        float d = red[0];
        dinv[i] = d > 0.f ? 1.f / sqrtf(d) : 0.f;
    }
}

// fused: bf16 M row + encoder F=2 aggregation (M @ yhat)
__global__ void k_dM2(const float* __restrict__ c, const float* __restrict__ dinv,
                      unsigned short* __restrict__ Mb, float* __restrict__ ax) {
    int i = blockIdx.x;
    int t = threadIdx.x;
    float xi = c[2 * i], yi = c[2 * i + 1], di = dinv[i];
    float a0 = 0.f, a1 = 0.f;
    for (int j = t; j < NN; j += 256) {
        float dx = xi - c[2 * j], dy = yi - c[2 * j + 1];
        float d = sqrtf(dx * dx + dy * dy);
        float w = (d > 0.f && d < 0.5f) ? 2.f * d : 0.f;
        float v = -(di * w) * dinv[j];
        Mb[(size_t)i * NN + j] = f2bf(v);
        a0 = fmaf(v, c[2 * j], a0);
        a1 = fmaf(v, c[2 * j + 1], a1);
    }
    __shared__ float r0[256], r1[256];
    r0[t] = a0;
    r1[t] = a1;
    __syncthreads();
    for (int off = 128; off > 0; off >>= 1) {
        if (t < off) { r0[t] += r0[t + off]; r1[t] += r1[t + off]; }
        __syncthreads();
    }
    if (t == 0) { ax[2 * i] = r0[0]; ax[2 * i + 1] = r1[0]; }
}

// dense agg via bf16 MFMA, X already bf16 (row-major [NN][F])
template <int F>
__global__ __launch_bounds__(256) void k_dmm_mfb(
    const unsigned short* __restrict__ Mb, const unsigned short* __restrict__ Xb,
    float* __restrict__ pbuf)
{
    __shared__ __align__(16) unsigned short Ms[64][72];
    __shared__ __align__(16) unsigned short Xs[64][72];
    const int tid = threadIdx.x;
    const int wid = tid >> 6, lane = tid & 63;
    const int m0 = blockIdx.x << 6, n0 = blockIdx.y << 6;
    const int kb0 = blockIdx.z << 8;
    const int lr = lane & 15;
    const int kg = lane >> 4;
    float4v acc[4];
#pragma unroll
    for (int t = 0; t < 4; t++) acc[t] = (float4v){0.f, 0.f, 0.f, 0.f};

    for (int kb = kb0; kb < kb0 + 256; kb += 64) {
#pragma unroll
        for (int it = 0; it < 2; it++) {
            int i = tid + it * 256;
            int r = i >> 3, c8 = (i & 7) << 3;
            *(short8v*)&Ms[r][c8] =
                *(const short8v*)&Mb[(size_t)(m0 + r) * NN + kb + c8];
        }
#pragma unroll
        for (int it = 0; it < 2; it++) {
            int i = tid + it * 256;
            int k2 = (i & 31) << 1;
            int n4 = (i >> 5) << 2;
            short4v va = *(const short4v*)&Xb[(size_t)(kb + k2) * F + n0 + n4];
            short4v vb = *(const short4v*)&Xb[(size_t)(kb + k2 + 1) * F + n0 + n4];
#pragma unroll
            for (int j = 0; j < 4; j++)
                *(unsigned*)&Xs[n4 + j][k2] =
                    (unsigned)(unsigned short)va[j] |
                    ((unsigned)(unsigned short)vb[j] << 16);
        }
        __syncthreads();
#pragma unroll
        for (int kh = 0; kh < 2; kh++) {
            int kk = kh * 32 + kg * 8;
            short8v a = *(const short8v*)&Ms[(wid << 4) + lr][kk];
#pragma unroll
            for (int t = 0; t < 4; t++) {
                short8v b = *(const short8v*)&Xs[(t << 4) + lr][kk];
                acc[t] = __builtin_amdgcn_mfma_f32_16x16x32_bf16(a, b, acc[t], 0, 0, 0);
            }
        }
        __syncthreads();
    }
    float* p = pbuf + (size_t)blockIdx.z * NN * F;
#pragma unroll
    for (int t = 0; t < 4; t++)
#pragma unroll
        for (int j = 0; j < 4; j++)
            p[(size_t)(m0 + (wid << 4) + (kg << 2) + j) * F + n0 + (t << 4) + lr] =
                acc[t][j];
}

template <int F, int NZ>
__global__ void k_redks(const float* __restrict__ pbuf, float* __restrict__ out) {
    const int TOT = NN * F / 4;
    int i = blockIdx.x * blockDim.x + threadIdx.x;
    if (i < TOT) {
        const float4* p = (const float4*)pbuf;
        float4 s = p[i];
#pragma unroll
        for (int z = 1; z < NZ; z++) {
            float4 v = p[(size_t)z * TOT + i];
            s.x += v.x; s.y += v.y; s.z += v.z; s.w += v.w;
        }
        ((float4*)out)[i] = s;
    }
}

// ---------------- bf16x3 MFMA GEMM segment core (r8 proven) ----------------
template <bool RELU>
__device__ __forceinline__ void mfma_seg(
    unsigned short (*Ah)[40], unsigned short (*Al)[40],
    unsigned short (*Bh)[40], unsigned short (*Bl)[40],
    const float* __restrict__ A, int lda,
    const float* __restrict__ B, int ldb, int K,
    int m0, int tid, int wid, int lr, int kg, float4v (&acc)[4])
{
    for (int k0 = 0; k0 < K; k0 += 32) {
        {   // stage A: 64 rows x 32 k, hi/lo
            int r = tid >> 2, k8 = (tid & 3) << 3;
            const float* ap = &A[(size_t)(m0 + r) * lda + k0 + k8];
            float4 va = *(const float4*)ap;
            float4 vb = *(const float4*)(ap + 4);
            float v[8] = {va.x, va.y, va.z, va.w, vb.x, vb.y, vb.z, vb.w};
            short8v hv, lv;
#pragma unroll
            for (int j = 0; j < 8; j++) {
                float f = RELU ? fmaxf(v[j], 0.f) : v[j];
                unsigned short h, l;
                bfsplit(f, h, l);
                hv[j] = (short)h; lv[j] = (short)l;
            }
            *(short8v*)&Ah[r][k8] = hv;
            *(short8v*)&Al[r][k8] = lv;
        }
        {   // stage B transposed: 64 cols x 32 k, hi/lo
            int k2 = (tid & 15) << 1;
            int n4 = (tid >> 4) << 2;
            const float* bp = &B[(size_t)(k0 + k2) * ldb + n4];
            float4 va = *(const float4*)bp;
            float4 vb = *(const float4*)(bp + ldb);
            float v0[4] = {va.x, va.y, va.z, va.w};
            float v1[4] = {vb.x, vb.y, vb.z, vb.w};
#pragma unroll
            for (int j = 0; j < 4; j++) {
                unsigned short h0, l0, h1, l1;
                bfsplit(v0[j], h0, l0);
                bfsplit(v1[j], h1, l1);
                *(unsigned*)&Bh[n4 + j][k2] = (unsigned)h0 | ((unsigned)h1 << 16);
                *(unsigned*)&Bl[n4 + j][k2] = (unsigned)l0 | ((unsigned)l1 << 16);
            }
        }
        __syncthreads();
        short8v ah = *(short8v*)&Ah[(wid << 4) + lr][kg << 3];
        short8v al = *(short8v*)&Al[(wid << 4) + lr][kg << 3];
#pragma unroll
        for (int t = 0; t < 4; t++) {
            short8v bh = *(short8v*)&Bh[(t << 4) + lr][kg << 3];
            short8v bl = *(short8v*)&Bl[(t << 4) + lr][kg << 3];
            acc[t] = __builtin_amdgcn_mfma_f32_16x16x32_bf16(ah, bh, acc[t], 0, 0, 0);
            acc[t] = __builtin_amdgcn_mfma_f32_16x16x32_bf16(ah, bl, acc[t], 0, 0, 0);
            acc[t] = __builtin_amdgcn_mfma_f32_16x16x32_bf16(al, bh, acc[t], 0, 0, 0);
        }
        __syncthreads();
    }
}

// z/r gates K-split (MFMA). K01 = 0 (enc) or LT (dec). Per-segment lda args.
__global__ __launch_bounds__(256) void k_zr_ks(
    const float* __restrict__ A0, int K01, const float* __restrict__ A1,
    const float* __restrict__ H, const float* __restrict__ A3,
    int la1, int la2, int la3,
    const float* __restrict__ Wx, const float* __restrict__ Wh,
    float* __restrict__ pbuf)
{
    __shared__ __align__(16) unsigned short Ah[64][40], Al[64][40],
                                            Bh[64][40], Bl[64][40];
    int tid = threadIdx.x;
    int wid = tid >> 6, lane = tid & 63, lr = lane & 15, kg = lane >> 4;
    int m0 = blockIdx.x << 6;
    int g = blockIdx.y >> 2;
    int n0 = (blockIdx.y & 3) << 6;
    float4v acc[4];
#pragma unroll
    for (int t = 0; t < 4; t++) acc[t] = (float4v){0.f, 0.f, 0.f, 0.f};
    const float* As[4] = {A0, A1, H, A3};
    const int ldas[4] = {K01, la1, la2, la3};
    const float* Bs[4] = {
        Wx + (size_t)(g * 2 + 0) * K01 * HE + n0,
        Wx + (size_t)(g * 2 + 1) * K01 * HE + n0,
        Wh + (size_t)(g * 2 + 0) * HE * HE + n0,
        Wh + (size_t)(g * 2 + 1) * HE * HE + n0};
    const int Ks[4] = {K01, K01, HE, HE};
    int chunk = (2 * K01 + 2 * HE) / ZR_NZ;
    int lo = blockIdx.z * chunk, hi = lo + chunk;
    int off = 0;
#pragma unroll
    for (int s = 0; s < 4; s++) {
        int a = lo - off; a = a < 0 ? 0 : a;
        int b = hi - off; b = b > Ks[s] ? Ks[s] : b;
        if (b > a)
            mfma_seg<false>(Ah, Al, Bh, Bl, As[s] + a, ldas[s],
                            Bs[s] + (size_t)a * HE, HE, b - a,
                            m0, tid, wid, lr, kg, acc);
        off += Ks[s];
    }
    float* p = pbuf + (size_t)blockIdx.z * NN * 512;
    int cbase = (g << 8) + n0;
#pragma unroll
    for (int t = 0; t < 4; t++)
#pragma unroll
        for (int j = 0; j < 4; j++)
            p[(size_t)(m0 + (wid << 4) + (kg << 2) + j) * 512 + cbase + (t << 4) + lr] =
                acc[t][j];
}

// epilogue: + rank-2 (x,aggx) terms when Wx != nullptr; writes hr + bf16 mirror
__global__ void k_zr_ep(const float* __restrict__ pbuf,
                        const float* __restrict__ bx, const float* __restrict__ bh,
                        const float* __restrict__ H,
                        const float* __restrict__ x2, const float* __restrict__ ax2,
                        const float* __restrict__ Wx,
                        float* __restrict__ gz, float* __restrict__ hr,
                        unsigned short* __restrict__ hrb)
{
    int i = blockIdx.x * 256 + threadIdx.x;  // < NN*512/4
    const float4* p = (const float4*)pbuf;
    const size_t S = (size_t)NN * 512 / 4;
    float4 a = p[i];
#pragma unroll
    for (int z = 1; z < ZR_NZ; z++) {
        float4 v = p[(size_t)z * S + i];
        a.x += v.x; a.y += v.y; a.z += v.z; a.w += v.w;
    }
    int row = i >> 7, c = (i & 127) << 2;
    int g = c >> 8, cc = c & 255;
    if (Wx) {
        float x0 = x2[2 * row], x1 = x2[2 * row + 1];
        float q0 = ax2[2 * row], q1 = ax2[2 * row + 1];
        const float* W0 = Wx + (size_t)(g * 2 + 0) * FIN * HE;
        const float* W1 = Wx + (size_t)(g * 2 + 1) * FIN * HE;
        float4 w00 = *(const float4*)&W0[cc];
        float4 w01 = *(const float4*)&W0[HE + cc];
        float4 w10 = *(const float4*)&W1[cc];
        float4 w11 = *(const float4*)&W1[HE + cc];
        a.x += x0 * w00.x + x1 * w01.x + q0 * w10.x + q1 * w11.x;
        a.y += x0 * w00.y + x1 * w01.y + q0 * w10.y + q1 * w11.y;
        a.z += x0 * w00.z + x1 * w01.z + q0 * w10.z + q1 * w11.z;
        a.w += x0 * w00.w + x1 * w01.w + q0 * w10.w + q1 * w11.w;
    }
    float4 b0 = *(const float4*)&bx[c];
    float4 b1 = *(const float4*)&bh[c];
    float4 s;
    s.x = 1.f / (1.f + expf(-(a.x + b0.x + b1.x)));
    s.y = 1.f / (1.f + expf(-(a.y + b0.y + b1.y)));
    s.z = 1.f / (1.f + expf(-(a.z + b0.z + b1.z)));
    s.w = 1.f / (1.f + expf(-(a.w + b0.w + b1.w)));
    if (c < HE) {
        *(float4*)&gz[(size_t)row * HE + c] = s;
    } else {
        size_t idx = (size_t)row * HE + cc;
        float4 h = *(const float4*)&H[idx];
        s.x *= h.x; s.y *= h.y; s.z *= h.z; s.w *= h.w;
        *(float4*)&hr[idx] = s;
        short4v sb;
        sb[0] = (short)f2bf(s.x); sb[1] = (short)f2bf(s.y);
        sb[2] = (short)f2bf(s.z); sb[3] = (short)f2bf(s.w);
        *(short4v*)&hrb[idx] = sb;
    }
}

// candidate gate K-split (MFMA)
__global__ __launch_bounds__(256) void k_gt_ks(
    const float* __restrict__ A0, int K01, const float* __restrict__ A1,
    const float* __restrict__ hr, const float* __restrict__ A3,
    int la1, int la2, int la3,
    const float* __restrict__ Wx2, const float* __restrict__ Wh2,
    float* __restrict__ pbuf)
{
    __shared__ __align__(16) unsigned short Ah[64][40], Al[64][40],
                                            Bh[64][40], Bl[64][40];
    int tid = threadIdx.x;
    int wid = tid >> 6, lane = tid & 63, lr = lane & 15, kg = lane >> 4;
    int m0 = blockIdx.x << 6;
    int n0 = blockIdx.y << 6;
    float4v acc[4];
#pragma unroll
    for (int t = 0; t < 4; t++) acc[t] = (float4v){0.f, 0.f, 0.f, 0.f};
    const float* As[4] = {A0, A1, hr, A3};
    const int ldas[4] = {K01, la1, la2, la3};
    const float* Bs[4] = {
        Wx2 + n0,
        Wx2 + (size_t)K01 * HE + n0,
        Wh2 + n0,
        Wh2 + (size_t)HE * HE + n0};
    const int Ks[4] = {K01, K01, HE, HE};
    int chunk = (2 * K01 + 2 * HE) / GT_NZ;
    int lo = blockIdx.z * chunk, hi = lo + chunk;
    int off = 0;
#pragma unroll
    for (int s = 0; s < 4; s++) {
        int a = lo - off; a = a < 0 ? 0 : a;
        int b = hi - off; b = b > Ks[s] ? Ks[s] : b;
        if (b > a)
            mfma_seg<false>(Ah, Al, Bh, Bl, As[s] + a, ldas[s],
                            Bs[s] + (size_t)a * HE, HE, b - a,
                            m0, tid, wid, lr, kg, acc);
        off += Ks[s];
    }
    float* p = pbuf + (size_t)blockIdx.z * NN * HE;
#pragma unroll
    for (int t = 0; t < 4; t++)
#pragma unroll
        for (int j = 0; j < 4; j++)
            p[(size_t)(m0 + (wid << 4) + (kg << 2) + j) * HE + n0 + (t << 4) + lr] =
                acc[t][j];
}

// epilogue: H = z*H + (1-z)*tanh(...); writes bf16 mirror at (Hb, ldhb)
__global__ void k_gt_ep(const float* __restrict__ pbuf,
                        const float* __restrict__ bx2, const float* __restrict__ bh2,
                        const float* __restrict__ gz,
                        const float* __restrict__ x2, const float* __restrict__ ax2,
                        const float* __restrict__ Wx2,
                        float* __restrict__ H,
                        unsigned short* __restrict__ Hb, int ldhb)
{
    int i = blockIdx.x * 256 + threadIdx.x;  // < NN*256/4
    const float4* p = (const float4*)pbuf;
    const size_t S = (size_t)NN * HE / 4;
    float4 a = p[i];
#pragma unroll
    for (int z = 1; z < GT_NZ; z++) {
        float4 v = p[(size_t)z * S + i];
        a.x += v.x; a.y += v.y; a.z += v.z; a.w += v.w;
    }
    int row = i >> 6, c = (i & 63) << 2;
    if (Wx2) {
        float x0 = x2[2 * row], x1 = x2[2 * row + 1];
        float q0 = ax2[2 * row], q1 = ax2[2 * row + 1];
        float4 w00 = *(const float4*)&Wx2[c];
        float4 w01 = *(const float4*)&Wx2[HE + c];
        float4 w10 = *(const float4*)&Wx2[2 * HE + c];
        float4 w11 = *(const float4*)&Wx2[3 * HE + c];
        a.x += x0 * w00.x + x1 * w01.x + q0 * w10.x + q1 * w11.x;
        a.y += x0 * w00.y + x1 * w01.y + q0 * w10.y + q1 * w11.y;
        a.z += x0 * w00.z + x1 * w01.z + q0 * w10.z + q1 * w11.z;
        a.w += x0 * w00.w + x1 * w01.w + q0 * w10.w + q1 * w11.w;
    }
    float4 b0 = *(const float4*)&bx2[c];
    float4 b1 = *(const float4*)&bh2[c];
    size_t idx = (size_t)row * HE + c;
    float4 z = *(const float4*)&gz[idx];
    float4 h = *(const float4*)&H[idx];
    float4 o;
    o.x = z.x * h.x + (1.f - z.x) * tanhf(a.x + b0.x + b1.x);
    o.y = z.y * h.y + (1.f - z.y) * tanhf(a.y + b0.y + b1.y);
    o.z = z.z * h.z + (1.f - z.z) * tanhf(a.z + b0.z + b1.z);
    o.w = z.w * h.w + (1.f - z.w) * tanhf(a.w + b0.w + b1.w);
    *(float4*)&H[idx] = o;
    short4v sb;
    sb[0] = (short)f2bf(o.x); sb[1] = (short)f2bf(o.y);
    sb[2] = (short)f2bf(o.z); sb[3] = (short)f2bf(o.w);
    *(short4v*)&Hb[(size_t)row * ldhb + c] = sb;
}

// latent linear K-split (MFMA, relu on A)
__global__ __launch_bounds__(256) void k_lin_ks(
    const float* __restrict__ A, const float* __restrict__ B,
    float* __restrict__ pbuf)
{
    __shared__ __align__(16) unsigned short Ah[64][40], Al[64][40],
                                            Bh[64][40], Bl[64][40];
    int tid = threadIdx.x;
    int wid = tid >> 6, lane = tid & 63, lr = lane & 15, kg = lane >> 4;
    int m0 = blockIdx.x << 6;
    int n0 = blockIdx.y << 6;
    int lo = blockIdx.z << 5;  // 32 per slice
    float4v acc[4];
#pragma unroll
    for (int t = 0; t < 4; t++) acc[t] = (float4v){0.f, 0.f, 0.f, 0.f};
    mfma_seg<true>(Ah, Al, Bh, Bl, A + lo, HE, B + (size_t)lo * LT + n0, LT, 32,
                   m0, tid, wid, lr, kg, acc);
    float* p = pbuf + (size_t)blockIdx.z * NN * LT;
#pragma unroll
    for (int t = 0; t < 4; t++)
#pragma unroll
        for (int j = 0; j < 4; j++)
            p[(size_t)(m0 + (wid << 4) + (kg << 2) + j) * LT + n0 + (t << 4) + lr] =
                acc[t][j];
}

// writes zlat fp32 + bf16 mirror into xcat_b[:, 0:128]
__global__ void k_lin_ep(const float* __restrict__ pbuf,
                         const float* __restrict__ bias, float* __restrict__ out,
                         unsigned short* __restrict__ zb)
{
    int i = blockIdx.x * 256 + threadIdx.x;  // < NN*128/4
    const float4* p = (const float4*)pbuf;
    const size_t S = (size_t)NN * LT / 4;
    int row = i >> 5, c = (i & 31) << 2;
    float4 bb = *(const float4*)&bias[c];
    float4 s = make_float4(bb.x, bb.y, bb.z, bb.w);
#pragma unroll
    for (int z = 0; z < LIN_NZ; z++) {
        float4 v = p[z * S + i];
        s.x += v.x; s.y += v.y; s.z += v.z; s.w += v.w;
    }
    ((float4*)out)[i] = s;
    short4v sb;
    sb[0] = (short)f2bf(s.x); sb[1] = (short)f2bf(s.y);
    sb[2] = (short)f2bf(s.z); sb[3] = (short)f2bf(s.w);
    *(short4v*)&zb[(size_t)row * XC + c] = sb;
}

// fp32 -> bf16 mirror with output stride (for initial states)
__global__ void k_cvtb(const float* __restrict__ in, unsigned short* __restrict__ outb,
                       int ldo) {
    int i = blockIdx.x * 256 + threadIdx.x;  // over NN*HE
    int r = i >> 8, c = i & 255;
    outb[(size_t)r * ldo + c] = f2bf(in[i]);
}

// y_hat = relu(H) @ dlinW + dlinb : one wave per row
__global__ void k_declin(const float* __restrict__ A, const float* __restrict__ B,
                         const float* __restrict__ bias, float* __restrict__ out) {
    int w = threadIdx.x >> 6, lane = threadIdx.x & 63;
    int m = blockIdx.x * 4 + w;
    float4 a = *(const float4*)&A[(size_t)m * HE + (lane << 2)];
    float av[4] = {a.x, a.y, a.z, a.w};
    float a0 = 0.f, a1 = 0.f;
#pragma unroll
    for (int j = 0; j < 4; j++) {
        float v = fmaxf(av[j], 0.f);
        float2 b = *(const float2*)&B[((lane << 2) + j) * 2];
        a0 = fmaf(v, b.x, a0);
        a1 = fmaf(v, b.y, a1);
    }
    for (int off = 32; off > 0; off >>= 1) {
        a0 += __shfl_down(a0, off, 64);
        a1 += __shfl_down(a1, off, 64);
    }
    if (lane == 0) {
        out[2 * m] = a0 + bias[0];
        out[2 * m + 1] = a1 + bias[1];
    }
}

extern "C" void kernel_launch(void* const* d_in, const int* in_sizes, int n_in,
                              void* d_out, int out_size, void* d_ws, size_t ws_size,
                              hipStream_t stream) {
    (void)in_sizes; (void)n_in; (void)out_size; (void)ws_size;
    const float* x_seq = (const float*)d_in[0];
    const int* ei = (const int*)d_in[1];
    const float* ews = (const float*)d_in[2];
    const float* h_enc_in = (const float*)d_in[3];
    const float* h_dec_in = (const float*)d_in[4];
    const float* encWx = (const float*)d_in[5];
    const float* encbx = (const float*)d_in[6];
    const float* encWh = (const float*)d_in[7];
    const float* encbh = (const float*)d_in[8];
    const float* elinW = (const float*)d_in[9];
    const float* elinb = (const float*)d_in[10];
    const float* decWx = (const float*)d_in[11];
    const float* decbx = (const float*)d_in[12];
    const float* decWh = (const float*)d_in[13];
    const float* decbh = (const float*)d_in[14];
    const float* dlinW = (const float*)d_in[15];
    const float* dlinb = (const float*)d_in[16];
    float* out = (float*)d_out;

    float* W = (float*)d_ws;
    float* h_enc = W; W += (size_t)NN * HE;
    float* h_dec = W; W += (size_t)NN * HE;
    float* aggh  = W; W += (size_t)NN * HE;
    float* hr    = W; W += (size_t)NN * HE;
    float* agghr = W; W += (size_t)NN * HE;
    float* gz    = W; W += (size_t)NN * HE;
    float* zlat  = W; W += (size_t)NN * LT;
    float* Y     = W; W += (size_t)NN * XC;   // combined decoder agg [aggx|aggh]
    float* yhat  = W; W += (size_t)NN * FIN;
    float* aggx2 = W; W += (size_t)NN * FIN;  // dense encoder F=2 agg
    float* dinv_d = W; W += NN;
    unsigned short* Mb = (unsigned short*)W; W += (size_t)NN * NN / 2;
    float* pbuf  = W; W += (size_t)DMM_NZ * NN * XC;  // 25.2 MB, max over all K-splits
    unsigned short* Hen_b = (unsigned short*)W; W += (size_t)NN * HE / 2;
    unsigned short* hr_b  = (unsigned short*)W; W += (size_t)NN * HE / 2;
    unsigned short* xcat_b = (unsigned short*)W; W += (size_t)NN * XC / 2;
    float* deg_all = W; W += (size_t)T_OBS * NN;
    int*   cnt_all = (int*)W; W += (size_t)T_OBS * NN;
    float* dinv_all = W; W += (size_t)T_OBS * NN;
    float* csr_nrm_all = W; W += (size_t)T_OBS * EE;
    float* aggx_all = W; W += (size_t)T_OBS * NN * FIN;
    int* roff_all = (int*)W; W += (size_t)T_OBS * (NN + 1) + 1;
    int* cur_all = (int*)W; W += (size_t)T_OBS * NN;
    int* csr_src_all = (int*)W; W += (size_t)T_OBS * EE;

    // ---- batched sparse prep ----
    hipMemsetAsync(deg_all, 0, sizeof(float) * T_OBS * NN * 2, stream);  // deg+cnt
    k_degcnt_lds<<<dim3(8, T_OBS), 256, 0, stream>>>(ei, ews, deg_all, cnt_all);
    k_scan_b<<<T_OBS, 256, 0, stream>>>(cnt_all, deg_all, roff_all, cur_all, dinv_all);
    k_scatter2_b<<<dim3(EE / 256, T_OBS), 256, 0, stream>>>(ei, ews, dinv_all, cur_all,
                                                            csr_src_all, csr_nrm_all);
    k_spmm2_b<<<dim3(NN / 256, T_OBS), 256, 0, stream>>>(roff_all, csr_src_all,
                                                         csr_nrm_all, x_seq, aggx_all);

    hipMemcpyAsync(h_enc, h_enc_in, sizeof(float) * NN * HE, hipMemcpyDeviceToDevice, stream);
    hipMemcpyAsync(h_dec, h_dec_in, sizeof(float) * NN * HE, hipMemcpyDeviceToDevice, stream);
    k_cvtb<<<NN * HE / 256, 256, 0, stream>>>(h_enc_in, Hen_b, HE);
    k_cvtb<<<NN * HE / 256, 256, 0, stream>>>(h_dec_in, xcat_b + LT, XC);

    for (int step = 0; step < T_OBS + PREDN - 1; ++step) {
        bool sparse = step < T_OBS;
        const float* xin;
        const float* aggx_s;
        const int* roff = roff_all + step * (NN + 1);
        const int* csr_src = csr_src_all + (size_t)step * EE;
        const float* csr_nrm = csr_nrm_all + (size_t)step * EE;
        if (sparse) {
            xin = x_seq + (size_t)step * NN * FIN;
            aggx_s = aggx_all + (size_t)step * NN * FIN;
        } else {
            k_ddeg<<<NN, 256, 0, stream>>>(yhat, dinv_d);
            k_dM2<<<NN, 256, 0, stream>>>(yhat, dinv_d, Mb, aggx2);
            xin = yhat;
            aggx_s = aggx2;
        }

        // ======= encoder GRU (x: F=2 via rank-2 epilogue, H: h_enc) =======
        if (sparse) {
            k_spmm_vb<HE, 64><<<NN / 4, 256, 0, stream>>>(roff, csr_src, csr_nrm,
                                                          Hen_b, aggh, HE);
        } else {
            k_dmm_mfb<HE><<<dim3(NN / 64, HE / 64, DMM_NZ), 256, 0, stream>>>(Mb, Hen_b, pbuf);
            k_redks<HE, DMM_NZ><<<NN * HE / 4 / 256, 256, 0, stream>>>(pbuf, aggh);
        }
        k_zr_ks<<<dim3(NN / 64, 8, ZR_NZ), 256, 0, stream>>>(xin, 0, aggx_s, h_enc, aggh,
                                                             FIN, HE, HE,
                                                             encWx, encWh, pbuf);
        k_zr_ep<<<NN * 512 / 4 / 256, 256, 0, stream>>>(pbuf, encbx, encbh, h_enc,
                                                        xin, aggx_s, encWx, gz, hr, hr_b);
        if (sparse) {
            k_spmm_vb<HE, 64><<<NN / 4, 256, 0, stream>>>(roff, csr_src, csr_nrm,
                                                          hr_b, agghr, HE);
        } else {
            k_dmm_mfb<HE><<<dim3(NN / 64, HE / 64, DMM_NZ), 256, 0, stream>>>(Mb, hr_b, pbuf);
            k_redks<HE, DMM_NZ><<<NN * HE / 4 / 256, 256, 0, stream>>>(pbuf, agghr);
        }
        k_gt_ks<<<dim3(NN / 64, 4, GT_NZ), 256, 0, stream>>>(xin, 0, aggx_s, hr, agghr,
                                                             FIN, HE, HE,
                                                             encWx + 4 * FIN * HE,
                                                             encWh + 4 * HE * HE, pbuf);
        k_gt_ep<<<NN * HE / 4 / 256, 256, 0, stream>>>(pbuf, encbx + 2 * HE,
                                                       encbh + 2 * HE, gz,
                                                       xin, aggx_s, encWx + 4 * FIN * HE,
                                                       h_enc, Hen_b, HE);
        k_lin_ks<<<dim3(NN / 64, 2, LIN_NZ), 256, 0, stream>>>(h_enc, elinW, pbuf);
        k_lin_ep<<<NN * LT / 4 / 256, 256, 0, stream>>>(pbuf, elinb, zlat, xcat_b);

        // ======= decoder GRU: combined agg of [zlat | h_dec] = xcat_b =======
        if (sparse) {
            k_spmm_vb<XC, 128><<<NN / 2, 256, 0, stream>>>(roff, csr_src, csr_nrm,
                                                           xcat_b, Y, XC);
        } else {
            k_dmm_mfb<XC><<<dim3(NN / 64, XC / 64, DMM_NZ), 256, 0, stream>>>(Mb, xcat_b, pbuf);
            k_redks<XC, DMM_NZ><<<NN * XC / 4 / 256, 256, 0, stream>>>(pbuf, Y);
        }
        k_zr_ks<<<dim3(NN / 64, 8, ZR_NZ), 256, 0, stream>>>(zlat, LT, Y, h_dec, Y + LT,
                                                             XC, HE, XC,
                                                             decWx, decWh, pbuf);
        k_zr_ep<<<NN * 512 / 4 / 256, 256, 0, stream>>>(pbuf, decbx, decbh, h_dec,
                                                        nullptr, nullptr, nullptr,
                                                        gz, hr, hr_b);
        if (sparse) {
            k_spmm_vb<HE, 64><<<NN / 4, 256, 0, stream>>>(roff, csr_src, csr_nrm,
                                                          hr_b, agghr, HE);
        } else {
            k_dmm_mfb<HE><<<dim3(NN / 64, HE / 64, DMM_NZ), 256, 0, stream>>>(Mb, hr_b, pbuf);
            k_redks<HE, DMM_NZ><<<NN * HE / 4 / 256, 256, 0, stream>>>(pbuf, agghr);
        }
        k_gt_ks<<<dim3(NN / 64, 4, GT_NZ), 256, 0, stream>>>(zlat, LT, Y, hr, agghr,
                                                             XC, HE, HE,
                                                             decWx + 4 * LT * HE,
                                                             decWh + 4 * HE * HE, pbuf);
        k_gt_ep<<<NN * HE / 4 / 256, 256, 0, stream>>>(pbuf, decbx + 2 * HE,
                                                       decbh + 2 * HE, gz,
                                                       nullptr, nullptr, nullptr,
                                                       h_dec, xcat_b + LT, XC);
        k_declin<<<NN / 4, 256, 0, stream>>>(h_dec, dlinW, dlinb, yhat);

        if (step >= T_OBS - 1) {
            hipMemcpyAsync(out + (size_t)(step - (T_OBS - 1)) * NN * FIN, yhat,
                           sizeof(float) * NN * FIN, hipMemcpyDeviceToDevice, stream);
        }
    }
}